// Round 1
// baseline (3438.886 us; speedup 1.0000x reference)
//
#include <hip/hip_runtime.h>
#include <hip/hip_bf16.h>
#include <math.h>

#define BATCH 2
#define SEQ   2048
#define DIM   2048
#define NH    16
#define HD    128
#define NROWS (BATCH * SEQ)   // 4096
#define EPS_RMS 1e-6f

// ===================================================================== GEMM
// C[M,N] = A[M,K] @ W[N,K]^T (+ bias). fp32 vector-ALU baseline.
// 64x64 tile, BK=16, 256 threads, 4x4 acc per thread.
#define BM 64
#define BN 64
#define BK 16

__global__ __launch_bounds__(256) void gemm_nt_kernel(
    const float* __restrict__ A, const float* __restrict__ W,
    const float* __restrict__ bias, float* __restrict__ C,
    const int M, const int N, const int K)
{
    // stride 68 floats = 272 B: 16B-aligned rows, conflict-free fp32x4 reads
    __shared__ float As[BK][BM + 4];
    __shared__ float Bs[BK][BN + 4];
    const int tid = threadIdx.x;
    const int tx = tid & 15;
    const int ty = tid >> 4;
    const int m0 = blockIdx.y * BM;
    const int n0 = blockIdx.x * BN;
    const int ldr = tid >> 2;          // 0..63 row of the staged tile
    const int ldc = (tid & 3) << 2;    // 0,4,8,12 col within BK

    float acc[4][4] = {};

    for (int k0 = 0; k0 < K; k0 += BK) {
        __syncthreads();
        const float4 av = *(const float4*)&A[(size_t)(m0 + ldr) * K + (k0 + ldc)];
        const float4 wv = *(const float4*)&W[(size_t)(n0 + ldr) * K + (k0 + ldc)];
        As[ldc + 0][ldr] = av.x; As[ldc + 1][ldr] = av.y;
        As[ldc + 2][ldr] = av.z; As[ldc + 3][ldr] = av.w;
        Bs[ldc + 0][ldr] = wv.x; Bs[ldc + 1][ldr] = wv.y;
        Bs[ldc + 2][ldr] = wv.z; Bs[ldc + 3][ldr] = wv.w;
        __syncthreads();
#pragma unroll
        for (int k = 0; k < BK; ++k) {
            const float4 a4 = *(const float4*)&As[k][ty << 2];
            const float4 b4 = *(const float4*)&Bs[k][tx << 2];
            const float aa[4] = {a4.x, a4.y, a4.z, a4.w};
            const float bb[4] = {b4.x, b4.y, b4.z, b4.w};
#pragma unroll
            for (int i = 0; i < 4; ++i)
#pragma unroll
                for (int j = 0; j < 4; ++j)
                    acc[i][j] = fmaf(aa[i], bb[j], acc[i][j]);
        }
    }

#pragma unroll
    for (int i = 0; i < 4; ++i) {
        const int row = m0 + (ty << 2) + i;
        const int col = n0 + (tx << 2);
        float4 ov;
        ov.x = acc[i][0]; ov.y = acc[i][1]; ov.z = acc[i][2]; ov.w = acc[i][3];
        if (bias != nullptr) {
            ov.x += bias[col + 0]; ov.y += bias[col + 1];
            ov.z += bias[col + 2]; ov.w += bias[col + 3];
        }
        *(float4*)&C[(size_t)row * N + col] = ov;
    }
}

// =============================================================== RMS + RoPE
// One block (256 thr) per row of [NROWS, DIM]. Norm over full DIM, then RoPE
// per head with interleaved pairs: angle = freqs[s, (e%HD)/2].
__global__ __launch_bounds__(256) void rmsnorm_rope_kernel(
    float* __restrict__ T, const float* __restrict__ g,
    const float* __restrict__ freqs)
{
    const int r = blockIdx.x;
    const int s = r & (SEQ - 1);
    const int tid = threadIdx.x;
    const int base = tid << 3;   // 8 elements per thread, same head, aligned pairs

    float v[8];
    *(float4*)&v[0] = *(const float4*)&T[(size_t)r * DIM + base];
    *(float4*)&v[4] = *(const float4*)&T[(size_t)r * DIM + base + 4];

    float ss = 0.f;
#pragma unroll
    for (int i = 0; i < 8; ++i) ss += v[i] * v[i];
#pragma unroll
    for (int off = 32; off > 0; off >>= 1) ss += __shfl_down(ss, off);

    __shared__ float wsum[4];
    __shared__ float inv_sh;
    if ((tid & 63) == 0) wsum[tid >> 6] = ss;
    __syncthreads();
    if (tid == 0)
        inv_sh = rsqrtf((wsum[0] + wsum[1] + wsum[2] + wsum[3]) * (1.0f / DIM) + EPS_RMS);
    __syncthreads();
    const float inv = inv_sh;

    float gg[8];
    *(float4*)&gg[0] = *(const float4*)&g[base];
    *(float4*)&gg[4] = *(const float4*)&g[base + 4];
#pragma unroll
    for (int i = 0; i < 8; ++i) v[i] *= inv * gg[i];

    const int p0 = (base & (HD - 1)) >> 1;
#pragma unroll
    for (int pp = 0; pp < 4; ++pp) {
        float sn, cs;
        __sincosf(freqs[(size_t)s * (HD / 2) + p0 + pp], &sn, &cs);
        const float t0 = v[2 * pp], t1 = v[2 * pp + 1];
        v[2 * pp]     = t0 * cs - t1 * sn;
        v[2 * pp + 1] = t0 * sn + t1 * cs;
    }

    *(float4*)&T[(size_t)r * DIM + base]     = *(float4*)&v[0];
    *(float4*)&T[(size_t)r * DIM + base + 4] = *(float4*)&v[4];
}

// ============================================================ Flash attention
// fp32 online-softmax. One block per (q-tile of 64, head, batch). 256 threads.
// Score phase: 4x4 scores/thread from transposed Qst/Kst (conflict-free b128).
// PV phase: 4 rows x 8 cols of O per thread in registers.
#define BQ  64
#define BKT 64

__global__ __launch_bounds__(256) void attn_kernel(
    const float* __restrict__ Q, const float* __restrict__ K,
    const float* __restrict__ V, const int* __restrict__ seq_lens,
    float* __restrict__ O)
{
    const int qt = blockIdx.x;
    const int h  = blockIdx.y;
    const int b  = blockIdx.z;
    const int len = seq_lens[b];
    const int q0 = qt * BQ;
    const float scale = 0.088388347648318447f;  // 128^-0.5

    __shared__ float Qst[HD][BQ + 4];    // [kk][qrow]
    __shared__ float Kst[HD][BKT + 4];   // [kk][krow]
    __shared__ float Vs[BKT][HD + 4];    // [krow][dd]
    __shared__ float Sc[BQ][BKT + 1];    // stride 65: conflict-free row scans
    __shared__ float mrow[BQ], lrow[BQ], alpha_s[BQ];

    const int tid = threadIdx.x;
    const int si0 = (tid >> 4) << 2;    // score rows
    const int sj0 = (tid & 15) << 2;    // score cols
    const int pi0 = (tid >> 4) << 2;    // PV rows
    const int pc0 = (tid & 15) << 3;    // PV cols (8 wide)

    // stage Q tile (transposed)
    for (int i = tid; i < BQ * HD / 4; i += 256) {
        const int e = i << 2;
        const int row = e >> 7;          // HD=128
        const int c0 = e & (HD - 1);
        const float4 qv = *(const float4*)&Q[(size_t)(b * SEQ + q0 + row) * DIM + h * HD + c0];
        Qst[c0 + 0][row] = qv.x; Qst[c0 + 1][row] = qv.y;
        Qst[c0 + 2][row] = qv.z; Qst[c0 + 3][row] = qv.w;
    }
    if (tid < BQ) { mrow[tid] = -3.0e38f; lrow[tid] = 0.f; }

    float o[4][8] = {};
    __syncthreads();

    const int ntiles = (len + BKT - 1) / BKT;
    for (int t = 0; t < ntiles; ++t) {
        const int k0 = t * BKT;
        __syncthreads();   // previous PV done with Vs/Sc
        for (int i = tid; i < BKT * HD / 4; i += 256) {
            const int e = i << 2;
            const int row = e >> 7;
            const int c0 = e & (HD - 1);
            const int kg = k0 + row;
            float4 kv = make_float4(0.f, 0.f, 0.f, 0.f);
            float4 vv = make_float4(0.f, 0.f, 0.f, 0.f);
            if (kg < len) {
                kv = *(const float4*)&K[(size_t)(b * SEQ + kg) * DIM + h * HD + c0];
                vv = *(const float4*)&V[(size_t)(b * SEQ + kg) * DIM + h * HD + c0];
            }
            Kst[c0 + 0][row] = kv.x; Kst[c0 + 1][row] = kv.y;
            Kst[c0 + 2][row] = kv.z; Kst[c0 + 3][row] = kv.w;
            *(float4*)&Vs[row][c0] = vv;
        }
        __syncthreads();

        // ---- scores: 4x4 per thread
        float acc[4][4] = {};
#pragma unroll 8
        for (int kk = 0; kk < HD; ++kk) {
            const float4 q4 = *(const float4*)&Qst[kk][si0];
            const float4 k4 = *(const float4*)&Kst[kk][sj0];
            const float qa[4] = {q4.x, q4.y, q4.z, q4.w};
            const float ka[4] = {k4.x, k4.y, k4.z, k4.w};
#pragma unroll
            for (int i = 0; i < 4; ++i)
#pragma unroll
                for (int j = 0; j < 4; ++j)
                    acc[i][j] = fmaf(qa[i], ka[j], acc[i][j]);
        }
#pragma unroll
        for (int i = 0; i < 4; ++i)
#pragma unroll
            for (int j = 0; j < 4; ++j) {
                const int jg = k0 + sj0 + j;
                Sc[si0 + i][sj0 + j] = (jg < len) ? acc[i][j] * scale : -1.0e9f;
            }
        __syncthreads();

        // ---- online softmax: one thread per row
        if (tid < BQ) {
            const int i = tid;
            const float m_old = mrow[i];
            float mx = m_old;
            for (int j = 0; j < BKT; ++j) mx = fmaxf(mx, Sc[i][j]);
            const float al = __expf(m_old - mx);
            float sum = 0.f;
            for (int j = 0; j < BKT; ++j) {
                const float p = __expf(Sc[i][j] - mx);
                Sc[i][j] = p;
                sum += p;
            }
            mrow[i] = mx;
            lrow[i] = lrow[i] * al + sum;
            alpha_s[i] = al;
        }
        __syncthreads();

        // ---- PV accumulate (registers)
#pragma unroll
        for (int i = 0; i < 4; ++i) {
            const float al = alpha_s[pi0 + i];
#pragma unroll
            for (int c = 0; c < 8; ++c) o[i][c] *= al;
        }
        for (int j = 0; j < BKT; ++j) {
            float p[4];
#pragma unroll
            for (int i = 0; i < 4; ++i) p[i] = Sc[pi0 + i][j];
            const float4 v0 = *(const float4*)&Vs[j][pc0];
            const float4 v1 = *(const float4*)&Vs[j][pc0 + 4];
            const float va[8] = {v0.x, v0.y, v0.z, v0.w, v1.x, v1.y, v1.z, v1.w};
#pragma unroll
            for (int i = 0; i < 4; ++i)
#pragma unroll
                for (int c = 0; c < 8; ++c)
                    o[i][c] = fmaf(p[i], va[c], o[i][c]);
        }
    }

    // ---- writeout
#pragma unroll
    for (int i = 0; i < 4; ++i) {
        const float invl = 1.0f / lrow[pi0 + i];
        float4 w0, w1;
        w0.x = o[i][0] * invl; w0.y = o[i][1] * invl;
        w0.z = o[i][2] * invl; w0.w = o[i][3] * invl;
        w1.x = o[i][4] * invl; w1.y = o[i][5] * invl;
        w1.z = o[i][6] * invl; w1.w = o[i][7] * invl;
        float* op = &O[(size_t)(b * SEQ + q0 + pi0 + i) * DIM + h * HD + pc0];
        *(float4*)&op[0] = w0;
        *(float4*)&op[4] = w1;
    }
}

// ==================================================================== launch
extern "C" void kernel_launch(void* const* d_in, const int* in_sizes, int n_in,
                              void* d_out, int out_size, void* d_ws, size_t ws_size,
                              hipStream_t stream)
{
    const float* x        = (const float*)d_in[0];
    const int*   seq_lens = (const int*)d_in[1];
    // d_in[2] = grid_sizes (int64) — unused by the reference computation
    const float* freqs    = (const float*)d_in[3];
    const float* Wq       = (const float*)d_in[4];
    const float* Wk       = (const float*)d_in[5];
    const float* Wv       = (const float*)d_in[6];
    const float* Wo       = (const float*)d_in[7];
    const float* bo       = (const float*)d_in[8];
    const float* gq       = (const float*)d_in[9];
    const float* gk       = (const float*)d_in[10];
    float* out = (float*)d_out;

    // workspace: Q | K | V | attn  (4 x 33.55 MB fp32 = 134 MB)
    const size_t mat = (size_t)NROWS * DIM;
    float* Qb = (float*)d_ws;
    float* Kb = Qb + mat;
    float* Vb = Kb + mat;
    float* Ab = Vb + mat;

    const dim3 gemm_grid(DIM / BN, NROWS / BM);
    gemm_nt_kernel<<<gemm_grid, 256, 0, stream>>>(x, Wq, nullptr, Qb, NROWS, DIM, DIM);
    gemm_nt_kernel<<<gemm_grid, 256, 0, stream>>>(x, Wk, nullptr, Kb, NROWS, DIM, DIM);
    gemm_nt_kernel<<<gemm_grid, 256, 0, stream>>>(x, Wv, nullptr, Vb, NROWS, DIM, DIM);

    rmsnorm_rope_kernel<<<NROWS, 256, 0, stream>>>(Qb, gq, freqs);
    rmsnorm_rope_kernel<<<NROWS, 256, 0, stream>>>(Kb, gk, freqs);

    attn_kernel<<<dim3(SEQ / BQ, NH, BATCH), 256, 0, stream>>>(Qb, Kb, Vb, seq_lens, Ab);

    gemm_nt_kernel<<<gemm_grid, 256, 0, stream>>>(Ab, Wo, bo, out, NROWS, DIM, DIM);
}

// Round 2
// 2001.448 us; speedup vs baseline: 1.7182x; 1.7182x over previous
//
#include <hip/hip_runtime.h>
#include <hip/hip_bf16.h>
#include <math.h>

#define BATCH 2
#define SEQ   2048
#define DIM   2048
#define NH    16
#define HD    128
#define NROWS (BATCH * SEQ)   // 4096
#define EPS_RMS 1e-6f

typedef unsigned short ushort_t;
typedef unsigned int   uint_t;
typedef __bf16 bf16x8 __attribute__((ext_vector_type(8)));
typedef float  f32x4  __attribute__((ext_vector_type(4)));

// ======================================================= fp32 -> bf16 hi/lo
__device__ inline ushort_t f2bf(float f) {
    uint_t u = __builtin_bit_cast(uint_t, f);
    uint_t r = u + 0x7FFFu + ((u >> 16) & 1u);   // RNE; inputs are finite/normal
    return (ushort_t)(r >> 16);
}

// 8 floats per thread -> 8 hi bf16 + 8 lo bf16 (16 B stores each)
__global__ __launch_bounds__(256) void split_bf16_kernel(
    const float* __restrict__ src, ushort_t* __restrict__ hi,
    ushort_t* __restrict__ lo, const int n)
{
    const int i = (blockIdx.x * 256 + threadIdx.x) << 3;
    if (i >= n) return;
    float v[8];
    *(float4*)&v[0] = *(const float4*)&src[i];
    *(float4*)&v[4] = *(const float4*)&src[i + 4];
    uint_t hp[4], lp[4];
#pragma unroll
    for (int j = 0; j < 4; ++j) {
        ushort_t h0 = f2bf(v[2 * j]);
        ushort_t h1 = f2bf(v[2 * j + 1]);
        float h0f = __builtin_bit_cast(float, (uint_t)h0 << 16);
        float h1f = __builtin_bit_cast(float, (uint_t)h1 << 16);
        ushort_t l0 = f2bf(v[2 * j] - h0f);
        ushort_t l1 = f2bf(v[2 * j + 1] - h1f);
        hp[j] = (uint_t)h0 | ((uint_t)h1 << 16);
        lp[j] = (uint_t)l0 | ((uint_t)l1 << 16);
    }
    *(uint4*)&hi[i] = make_uint4(hp[0], hp[1], hp[2], hp[3]);
    *(uint4*)&lo[i] = make_uint4(lp[0], lp[1], lp[2], lp[3]);
}

// ============================================= split-bf16 MFMA GEMM (3-term)
// C[M,N] = (Ah+Al)[M,K] @ (Bh+Bl)[N,K]^T (+bias), dropping Al*Bl (~2^-16).
// 128x128 tile, BK=32, 256 thr = 4 waves in 2x2, 4x4 MFMAs of 16x16x32/wave.
// LDS tiles unpadded K-major (required by global_load_lds lane mapping).
__global__ __launch_bounds__(256, 2) void gemm_bf16x3_kernel(
    const ushort_t* __restrict__ Ah, const ushort_t* __restrict__ Al,
    const ushort_t* __restrict__ Bh, const ushort_t* __restrict__ Bl,
    const float* __restrict__ bias, float* __restrict__ C,
    const int M, const int N, const int K)
{
    __shared__ __align__(16) ushort_t sAh[4096], sAl[4096], sBh[4096], sBl[4096];
    const int tid  = threadIdx.x;
    const int w    = tid >> 6;
    const int lane = tid & 63;
    const int m0 = blockIdx.y * 128;
    const int n0 = blockIdx.x * 128;

    const int scol = (lane & 3) << 3;       // 0,8,16,24 within BK=32
    const int wr = w >> 1, wc = w & 1;
    const int fr = lane & 15, quad = lane >> 4;

    f32x4 acc[4][4];
#pragma unroll
    for (int mi = 0; mi < 4; ++mi)
#pragma unroll
        for (int ni = 0; ni < 4; ++ni)
            acc[mi][ni] = (f32x4){0.f, 0.f, 0.f, 0.f};

    for (int k0 = 0; k0 < K; k0 += 32) {
        __syncthreads();
#pragma unroll
        for (int it = 0; it < 2; ++it) {
            const int row  = (w << 5) + (it << 4) + (lane >> 2); // 0..127
            const int loff = (w << 10) + (it << 9);              // wave-uniform elems
            const size_t ga = (size_t)(m0 + row) * K + k0 + scol;
            const size_t gb = (size_t)(n0 + row) * K + k0 + scol;
            __builtin_amdgcn_global_load_lds(
                (const __attribute__((address_space(1))) uint_t*)(const void*)(Ah + ga),
                (__attribute__((address_space(3))) uint_t*)(void*)&sAh[loff], 16, 0, 0);
            __builtin_amdgcn_global_load_lds(
                (const __attribute__((address_space(1))) uint_t*)(const void*)(Al + ga),
                (__attribute__((address_space(3))) uint_t*)(void*)&sAl[loff], 16, 0, 0);
            __builtin_amdgcn_global_load_lds(
                (const __attribute__((address_space(1))) uint_t*)(const void*)(Bh + gb),
                (__attribute__((address_space(3))) uint_t*)(void*)&sBh[loff], 16, 0, 0);
            __builtin_amdgcn_global_load_lds(
                (const __attribute__((address_space(1))) uint_t*)(const void*)(Bl + gb),
                (__attribute__((address_space(3))) uint_t*)(void*)&sBl[loff], 16, 0, 0);
        }
        __syncthreads();

        bf16x8 bh[4], bl[4];
#pragma unroll
        for (int ni = 0; ni < 4; ++ni) {
            const int row = (wc << 6) + (ni << 4) + fr;
            bh[ni] = *(const bf16x8*)&sBh[(row << 5) + (quad << 3)];
            bl[ni] = *(const bf16x8*)&sBl[(row << 5) + (quad << 3)];
        }
#pragma unroll
        for (int mi = 0; mi < 4; ++mi) {
            const int row = (wr << 6) + (mi << 4) + fr;
            const bf16x8 ah = *(const bf16x8*)&sAh[(row << 5) + (quad << 3)];
            const bf16x8 al = *(const bf16x8*)&sAl[(row << 5) + (quad << 3)];
#pragma unroll
            for (int ni = 0; ni < 4; ++ni) {
                acc[mi][ni] = __builtin_amdgcn_mfma_f32_16x16x32_bf16(ah, bh[ni], acc[mi][ni], 0, 0, 0);
                acc[mi][ni] = __builtin_amdgcn_mfma_f32_16x16x32_bf16(ah, bl[ni], acc[mi][ni], 0, 0, 0);
                acc[mi][ni] = __builtin_amdgcn_mfma_f32_16x16x32_bf16(al, bh[ni], acc[mi][ni], 0, 0, 0);
            }
        }
    }

#pragma unroll
    for (int mi = 0; mi < 4; ++mi)
#pragma unroll
        for (int ni = 0; ni < 4; ++ni) {
            const int col = n0 + (wc << 6) + (ni << 4) + fr;
            const float bv = bias ? bias[col] : 0.f;
#pragma unroll
            for (int r = 0; r < 4; ++r) {
                const int rowg = m0 + (wr << 6) + (mi << 4) + (quad << 2) + r;
                C[(size_t)rowg * N + col] = acc[mi][ni][r] + bv;
            }
        }
}

// ===================================================================== GEMM (fp32 fallback)
#define BM 64
#define BN 64
#define BK 16

__global__ __launch_bounds__(256) void gemm_nt_kernel(
    const float* __restrict__ A, const float* __restrict__ W,
    const float* __restrict__ bias, float* __restrict__ C,
    const int M, const int N, const int K)
{
    __shared__ float As[BK][BM + 4];
    __shared__ float Bs[BK][BN + 4];
    const int tid = threadIdx.x;
    const int tx = tid & 15;
    const int ty = tid >> 4;
    const int m0 = blockIdx.y * BM;
    const int n0 = blockIdx.x * BN;
    const int ldr = tid >> 2;
    const int ldc = (tid & 3) << 2;

    float acc[4][4] = {};

    for (int k0 = 0; k0 < K; k0 += BK) {
        __syncthreads();
        const float4 av = *(const float4*)&A[(size_t)(m0 + ldr) * K + (k0 + ldc)];
        const float4 wv = *(const float4*)&W[(size_t)(n0 + ldr) * K + (k0 + ldc)];
        As[ldc + 0][ldr] = av.x; As[ldc + 1][ldr] = av.y;
        As[ldc + 2][ldr] = av.z; As[ldc + 3][ldr] = av.w;
        Bs[ldc + 0][ldr] = wv.x; Bs[ldc + 1][ldr] = wv.y;
        Bs[ldc + 2][ldr] = wv.z; Bs[ldc + 3][ldr] = wv.w;
        __syncthreads();
#pragma unroll
        for (int k = 0; k < BK; ++k) {
            const float4 a4 = *(const float4*)&As[k][ty << 2];
            const float4 b4 = *(const float4*)&Bs[k][tx << 2];
            const float aa[4] = {a4.x, a4.y, a4.z, a4.w};
            const float bb[4] = {b4.x, b4.y, b4.z, b4.w};
#pragma unroll
            for (int i = 0; i < 4; ++i)
#pragma unroll
                for (int j = 0; j < 4; ++j)
                    acc[i][j] = fmaf(aa[i], bb[j], acc[i][j]);
        }
    }

#pragma unroll
    for (int i = 0; i < 4; ++i) {
        const int row = m0 + (ty << 2) + i;
        const int col = n0 + (tx << 2);
        float4 ov;
        ov.x = acc[i][0]; ov.y = acc[i][1]; ov.z = acc[i][2]; ov.w = acc[i][3];
        if (bias != nullptr) {
            ov.x += bias[col + 0]; ov.y += bias[col + 1];
            ov.z += bias[col + 2]; ov.w += bias[col + 3];
        }
        *(float4*)&C[(size_t)row * N + col] = ov;
    }
}

// =============================================================== RMS + RoPE
__global__ __launch_bounds__(256) void rmsnorm_rope_kernel(
    float* __restrict__ T, const float* __restrict__ g,
    const float* __restrict__ freqs)
{
    const int r = blockIdx.x;
    const int s = r & (SEQ - 1);
    const int tid = threadIdx.x;
    const int base = tid << 3;

    float v[8];
    *(float4*)&v[0] = *(const float4*)&T[(size_t)r * DIM + base];
    *(float4*)&v[4] = *(const float4*)&T[(size_t)r * DIM + base + 4];

    float ss = 0.f;
#pragma unroll
    for (int i = 0; i < 8; ++i) ss += v[i] * v[i];
#pragma unroll
    for (int off = 32; off > 0; off >>= 1) ss += __shfl_down(ss, off);

    __shared__ float wsum[4];
    __shared__ float inv_sh;
    if ((tid & 63) == 0) wsum[tid >> 6] = ss;
    __syncthreads();
    if (tid == 0)
        inv_sh = rsqrtf((wsum[0] + wsum[1] + wsum[2] + wsum[3]) * (1.0f / DIM) + EPS_RMS);
    __syncthreads();
    const float inv = inv_sh;

    float gg[8];
    *(float4*)&gg[0] = *(const float4*)&g[base];
    *(float4*)&gg[4] = *(const float4*)&g[base + 4];
#pragma unroll
    for (int i = 0; i < 8; ++i) v[i] *= inv * gg[i];

    const int p0 = (base & (HD - 1)) >> 1;
#pragma unroll
    for (int pp = 0; pp < 4; ++pp) {
        float sn, cs;
        __sincosf(freqs[(size_t)s * (HD / 2) + p0 + pp], &sn, &cs);
        const float t0 = v[2 * pp], t1 = v[2 * pp + 1];
        v[2 * pp]     = t0 * cs - t1 * sn;
        v[2 * pp + 1] = t0 * sn + t1 * cs;
    }

    *(float4*)&T[(size_t)r * DIM + base]     = *(float4*)&v[0];
    *(float4*)&T[(size_t)r * DIM + base + 4] = *(float4*)&v[4];
}

// ============================================================ Flash attention
#define BQ  64
#define BKT 64

__global__ __launch_bounds__(256) void attn_kernel(
    const float* __restrict__ Q, const float* __restrict__ K,
    const float* __restrict__ V, const int* __restrict__ seq_lens,
    float* __restrict__ O)
{
    const int qt = blockIdx.x;
    const int h  = blockIdx.y;
    const int b  = blockIdx.z;
    const int len = seq_lens[b];
    const int q0 = qt * BQ;
    const float scale = 0.088388347648318447f;  // 128^-0.5

    __shared__ float Qst[HD][BQ + 4];
    __shared__ float Kst[HD][BKT + 4];
    __shared__ float Vs[BKT][HD + 4];
    __shared__ float Sc[BQ][BKT + 1];
    __shared__ float mrow[BQ], lrow[BQ], alpha_s[BQ];

    const int tid = threadIdx.x;
    const int si0 = (tid >> 4) << 2;
    const int sj0 = (tid & 15) << 2;
    const int pi0 = (tid >> 4) << 2;
    const int pc0 = (tid & 15) << 3;

    for (int i = tid; i < BQ * HD / 4; i += 256) {
        const int e = i << 2;
        const int row = e >> 7;
        const int c0 = e & (HD - 1);
        const float4 qv = *(const float4*)&Q[(size_t)(b * SEQ + q0 + row) * DIM + h * HD + c0];
        Qst[c0 + 0][row] = qv.x; Qst[c0 + 1][row] = qv.y;
        Qst[c0 + 2][row] = qv.z; Qst[c0 + 3][row] = qv.w;
    }
    if (tid < BQ) { mrow[tid] = -3.0e38f; lrow[tid] = 0.f; }

    float o[4][8] = {};
    __syncthreads();

    const int ntiles = (len + BKT - 1) / BKT;
    for (int t = 0; t < ntiles; ++t) {
        const int k0 = t * BKT;
        __syncthreads();
        for (int i = tid; i < BKT * HD / 4; i += 256) {
            const int e = i << 2;
            const int row = e >> 7;
            const int c0 = e & (HD - 1);
            const int kg = k0 + row;
            float4 kv = make_float4(0.f, 0.f, 0.f, 0.f);
            float4 vv = make_float4(0.f, 0.f, 0.f, 0.f);
            if (kg < len) {
                kv = *(const float4*)&K[(size_t)(b * SEQ + kg) * DIM + h * HD + c0];
                vv = *(const float4*)&V[(size_t)(b * SEQ + kg) * DIM + h * HD + c0];
            }
            Kst[c0 + 0][row] = kv.x; Kst[c0 + 1][row] = kv.y;
            Kst[c0 + 2][row] = kv.z; Kst[c0 + 3][row] = kv.w;
            *(float4*)&Vs[row][c0] = vv;
        }
        __syncthreads();

        float acc[4][4] = {};
#pragma unroll 8
        for (int kk = 0; kk < HD; ++kk) {
            const float4 q4 = *(const float4*)&Qst[kk][si0];
            const float4 k4 = *(const float4*)&Kst[kk][sj0];
            const float qa[4] = {q4.x, q4.y, q4.z, q4.w};
            const float ka[4] = {k4.x, k4.y, k4.z, k4.w};
#pragma unroll
            for (int i = 0; i < 4; ++i)
#pragma unroll
                for (int j = 0; j < 4; ++j)
                    acc[i][j] = fmaf(qa[i], ka[j], acc[i][j]);
        }
#pragma unroll
        for (int i = 0; i < 4; ++i)
#pragma unroll
            for (int j = 0; j < 4; ++j) {
                const int jg = k0 + sj0 + j;
                Sc[si0 + i][sj0 + j] = (jg < len) ? acc[i][j] * scale : -1.0e9f;
            }
        __syncthreads();

        if (tid < BQ) {
            const int i = tid;
            const float m_old = mrow[i];
            float mx = m_old;
            for (int j = 0; j < BKT; ++j) mx = fmaxf(mx, Sc[i][j]);
            const float al = __expf(m_old - mx);
            float sum = 0.f;
            for (int j = 0; j < BKT; ++j) {
                const float p = __expf(Sc[i][j] - mx);
                Sc[i][j] = p;
                sum += p;
            }
            mrow[i] = mx;
            lrow[i] = lrow[i] * al + sum;
            alpha_s[i] = al;
        }
        __syncthreads();

#pragma unroll
        for (int i = 0; i < 4; ++i) {
            const float al = alpha_s[pi0 + i];
#pragma unroll
            for (int c = 0; c < 8; ++c) o[i][c] *= al;
        }
        for (int j = 0; j < BKT; ++j) {
            float p[4];
#pragma unroll
            for (int i = 0; i < 4; ++i) p[i] = Sc[pi0 + i][j];
            const float4 v0 = *(const float4*)&Vs[j][pc0];
            const float4 v1 = *(const float4*)&Vs[j][pc0 + 4];
            const float va[8] = {v0.x, v0.y, v0.z, v0.w, v1.x, v1.y, v1.z, v1.w};
#pragma unroll
            for (int i = 0; i < 4; ++i)
#pragma unroll
                for (int c = 0; c < 8; ++c)
                    o[i][c] = fmaf(p[i], va[c], o[i][c]);
        }
    }

#pragma unroll
    for (int i = 0; i < 4; ++i) {
        const float invl = 1.0f / lrow[pi0 + i];
        float4 w0, w1;
        w0.x = o[i][0] * invl; w0.y = o[i][1] * invl;
        w0.z = o[i][2] * invl; w0.w = o[i][3] * invl;
        w1.x = o[i][4] * invl; w1.y = o[i][5] * invl;
        w1.z = o[i][6] * invl; w1.w = o[i][7] * invl;
        float* op = &O[(size_t)(b * SEQ + q0 + pi0 + i) * DIM + h * HD + pc0];
        *(float4*)&op[0] = w0;
        *(float4*)&op[4] = w1;
    }
}

// ==================================================================== launch
extern "C" void kernel_launch(void* const* d_in, const int* in_sizes, int n_in,
                              void* d_out, int out_size, void* d_ws, size_t ws_size,
                              hipStream_t stream)
{
    const float* x        = (const float*)d_in[0];
    const int*   seq_lens = (const int*)d_in[1];
    const float* freqs    = (const float*)d_in[3];
    const float* Wq       = (const float*)d_in[4];
    const float* Wk       = (const float*)d_in[5];
    const float* Wv       = (const float*)d_in[6];
    const float* Wo       = (const float*)d_in[7];
    const float* bo       = (const float*)d_in[8];
    const float* gq       = (const float*)d_in[9];
    const float* gk       = (const float*)d_in[10];
    float* out = (float*)d_out;

    const size_t mat = (size_t)NROWS * DIM;       // 8.39M elems
    const size_t wsz = (size_t)DIM * DIM;         // 4.19M elems

    float* Qb = (float*)d_ws;
    float* Kb = Qb + mat;
    float* Vb = Kb + mat;
    float* Ab = Vb + mat;

    // bf16 split region (after the 4 fp32 matrices)
    ushort_t* xh  = (ushort_t*)(Ab + mat);
    ushort_t* xl  = xh + mat;       // xh/xl reused for attn-output split later
    ushort_t* wqh = xl + mat;
    ushort_t* wql = wqh + wsz;
    ushort_t* wkh = wql + wsz;
    ushort_t* wkl = wkh + wsz;
    ushort_t* wvh = wkl + wsz;
    ushort_t* wvl = wvh + wsz;
    ushort_t* woh = wvl + wsz;
    ushort_t* wol = woh + wsz;

    const size_t need_bytes = (4 * mat) * sizeof(float)
                            + (2 * mat + 8 * wsz) * sizeof(ushort_t);

    const dim3 attn_grid(SEQ / BQ, NH, BATCH);

    if (ws_size >= need_bytes) {
        // ---- split inputs to bf16 hi/lo
        split_bf16_kernel<<<(int)(mat / (256 * 8)), 256, 0, stream>>>(x, xh, xl, (int)mat);
        split_bf16_kernel<<<(int)(wsz / (256 * 8)), 256, 0, stream>>>(Wq, wqh, wql, (int)wsz);
        split_bf16_kernel<<<(int)(wsz / (256 * 8)), 256, 0, stream>>>(Wk, wkh, wkl, (int)wsz);
        split_bf16_kernel<<<(int)(wsz / (256 * 8)), 256, 0, stream>>>(Wv, wvh, wvl, (int)wsz);
        split_bf16_kernel<<<(int)(wsz / (256 * 8)), 256, 0, stream>>>(Wo, woh, wol, (int)wsz);

        const dim3 gg(DIM / 128, NROWS / 128);
        gemm_bf16x3_kernel<<<gg, 256, 0, stream>>>(xh, xl, wqh, wql, nullptr, Qb, NROWS, DIM, DIM);
        gemm_bf16x3_kernel<<<gg, 256, 0, stream>>>(xh, xl, wkh, wkl, nullptr, Kb, NROWS, DIM, DIM);
        gemm_bf16x3_kernel<<<gg, 256, 0, stream>>>(xh, xl, wvh, wvl, nullptr, Vb, NROWS, DIM, DIM);

        rmsnorm_rope_kernel<<<NROWS, 256, 0, stream>>>(Qb, gq, freqs);
        rmsnorm_rope_kernel<<<NROWS, 256, 0, stream>>>(Kb, gk, freqs);

        attn_kernel<<<attn_grid, 256, 0, stream>>>(Qb, Kb, Vb, seq_lens, Ab);

        split_bf16_kernel<<<(int)(mat / (256 * 8)), 256, 0, stream>>>(Ab, xh, xl, (int)mat);
        gemm_bf16x3_kernel<<<gg, 256, 0, stream>>>(xh, xl, woh, wol, bo, out, NROWS, DIM, DIM);
    } else {
        // ---- fallback: fp32 vector-ALU GEMMs (known-correct round-1 path)
        const dim3 gemm_grid(DIM / BN, NROWS / BM);
        gemm_nt_kernel<<<gemm_grid, 256, 0, stream>>>(x, Wq, nullptr, Qb, NROWS, DIM, DIM);
        gemm_nt_kernel<<<gemm_grid, 256, 0, stream>>>(x, Wk, nullptr, Kb, NROWS, DIM, DIM);
        gemm_nt_kernel<<<gemm_grid, 256, 0, stream>>>(x, Wv, nullptr, Vb, NROWS, DIM, DIM);
        rmsnorm_rope_kernel<<<NROWS, 256, 0, stream>>>(Qb, gq, freqs);
        rmsnorm_rope_kernel<<<NROWS, 256, 0, stream>>>(Kb, gk, freqs);
        attn_kernel<<<attn_grid, 256, 0, stream>>>(Qb, Kb, Vb, seq_lens, Ab);
        gemm_nt_kernel<<<gemm_grid, 256, 0, stream>>>(Ab, Wo, bo, out, NROWS, DIM, DIM);
    }
}

// Round 3
// 1981.496 us; speedup vs baseline: 1.7355x; 1.0101x over previous
//
#include <hip/hip_runtime.h>
#include <hip/hip_bf16.h>
#include <math.h>

#define BATCH 2
#define SEQ   2048
#define DIM   2048
#define NH    16
#define HD    128
#define NROWS (BATCH * SEQ)   // 4096
#define EPS_RMS 1e-6f

typedef unsigned short ushort_t;
typedef unsigned int   uint_t;
typedef __bf16 bf16x8 __attribute__((ext_vector_type(8)));
typedef float  f32x4  __attribute__((ext_vector_type(4)));

// ======================================================= fp32 -> bf16 (RNE)
__device__ inline ushort_t f2bf(float f) {
    uint_t u = __builtin_bit_cast(uint_t, f);
    uint_t r = u + 0x7FFFu + ((u >> 16) & 1u);
    return (ushort_t)(r >> 16);
}

// 8 floats per thread -> 8 hi bf16 + 8 lo bf16
__global__ __launch_bounds__(256) void split_bf16_kernel(
    const float* __restrict__ src, ushort_t* __restrict__ hi,
    ushort_t* __restrict__ lo, const int n)
{
    const int i = (blockIdx.x * 256 + threadIdx.x) << 3;
    if (i >= n) return;
    float v[8];
    *(float4*)&v[0] = *(const float4*)&src[i];
    *(float4*)&v[4] = *(const float4*)&src[i + 4];
    uint_t hp[4], lp[4];
#pragma unroll
    for (int j = 0; j < 4; ++j) {
        ushort_t h0 = f2bf(v[2 * j]);
        ushort_t h1 = f2bf(v[2 * j + 1]);
        float h0f = __builtin_bit_cast(float, (uint_t)h0 << 16);
        float h1f = __builtin_bit_cast(float, (uint_t)h1 << 16);
        ushort_t l0 = f2bf(v[2 * j] - h0f);
        ushort_t l1 = f2bf(v[2 * j + 1] - h1f);
        hp[j] = (uint_t)h0 | ((uint_t)h1 << 16);
        lp[j] = (uint_t)l0 | ((uint_t)l1 << 16);
    }
    *(uint4*)&hi[i] = make_uint4(hp[0], hp[1], hp[2], hp[3]);
    *(uint4*)&lo[i] = make_uint4(lp[0], lp[1], lp[2], lp[3]);
}

// ============================================= split-bf16 MFMA GEMM (3-term)
__global__ __launch_bounds__(256, 2) void gemm_bf16x3_kernel(
    const ushort_t* __restrict__ Ah, const ushort_t* __restrict__ Al,
    const ushort_t* __restrict__ Bh, const ushort_t* __restrict__ Bl,
    const float* __restrict__ bias, float* __restrict__ C,
    const int M, const int N, const int K)
{
    __shared__ __align__(16) ushort_t sAh[4096], sAl[4096], sBh[4096], sBl[4096];
    const int tid  = threadIdx.x;
    const int w    = tid >> 6;
    const int lane = tid & 63;
    const int m0 = blockIdx.y * 128;
    const int n0 = blockIdx.x * 128;

    const int scol = (lane & 3) << 3;
    const int wr = w >> 1, wc = w & 1;
    const int fr = lane & 15, quad = lane >> 4;

    f32x4 acc[4][4];
#pragma unroll
    for (int mi = 0; mi < 4; ++mi)
#pragma unroll
        for (int ni = 0; ni < 4; ++ni)
            acc[mi][ni] = (f32x4){0.f, 0.f, 0.f, 0.f};

    for (int k0 = 0; k0 < K; k0 += 32) {
        __syncthreads();
#pragma unroll
        for (int it = 0; it < 2; ++it) {
            const int row  = (w << 5) + (it << 4) + (lane >> 2);
            const int loff = (w << 10) + (it << 9);
            const size_t ga = (size_t)(m0 + row) * K + k0 + scol;
            const size_t gb = (size_t)(n0 + row) * K + k0 + scol;
            __builtin_amdgcn_global_load_lds(
                (const __attribute__((address_space(1))) uint_t*)(const void*)(Ah + ga),
                (__attribute__((address_space(3))) uint_t*)(void*)&sAh[loff], 16, 0, 0);
            __builtin_amdgcn_global_load_lds(
                (const __attribute__((address_space(1))) uint_t*)(const void*)(Al + ga),
                (__attribute__((address_space(3))) uint_t*)(void*)&sAl[loff], 16, 0, 0);
            __builtin_amdgcn_global_load_lds(
                (const __attribute__((address_space(1))) uint_t*)(const void*)(Bh + gb),
                (__attribute__((address_space(3))) uint_t*)(void*)&sBh[loff], 16, 0, 0);
            __builtin_amdgcn_global_load_lds(
                (const __attribute__((address_space(1))) uint_t*)(const void*)(Bl + gb),
                (__attribute__((address_space(3))) uint_t*)(void*)&sBl[loff], 16, 0, 0);
        }
        __syncthreads();

        bf16x8 bh[4], bl[4];
#pragma unroll
        for (int ni = 0; ni < 4; ++ni) {
            const int row = (wc << 6) + (ni << 4) + fr;
            bh[ni] = *(const bf16x8*)&sBh[(row << 5) + (quad << 3)];
            bl[ni] = *(const bf16x8*)&sBl[(row << 5) + (quad << 3)];
        }
#pragma unroll
        for (int mi = 0; mi < 4; ++mi) {
            const int row = (wr << 6) + (mi << 4) + fr;
            const bf16x8 ah = *(const bf16x8*)&sAh[(row << 5) + (quad << 3)];
            const bf16x8 al = *(const bf16x8*)&sAl[(row << 5) + (quad << 3)];
#pragma unroll
            for (int ni = 0; ni < 4; ++ni) {
                acc[mi][ni] = __builtin_amdgcn_mfma_f32_16x16x32_bf16(ah, bh[ni], acc[mi][ni], 0, 0, 0);
                acc[mi][ni] = __builtin_amdgcn_mfma_f32_16x16x32_bf16(ah, bl[ni], acc[mi][ni], 0, 0, 0);
                acc[mi][ni] = __builtin_amdgcn_mfma_f32_16x16x32_bf16(al, bh[ni], acc[mi][ni], 0, 0, 0);
            }
        }
    }

#pragma unroll
    for (int mi = 0; mi < 4; ++mi)
#pragma unroll
        for (int ni = 0; ni < 4; ++ni) {
            const int col = n0 + (wc << 6) + (ni << 4) + fr;
            const float bv = bias ? bias[col] : 0.f;
#pragma unroll
            for (int r = 0; r < 4; ++r) {
                const int rowg = m0 + (wr << 6) + (mi << 4) + (quad << 2) + r;
                C[(size_t)rowg * N + col] = acc[mi][ni][r] + bv;
            }
        }
}

// ===================================================================== GEMM (fp32 fallback)
#define BM 64
#define BN 64
#define BK 16

__global__ __launch_bounds__(256) void gemm_nt_kernel(
    const float* __restrict__ A, const float* __restrict__ W,
    const float* __restrict__ bias, float* __restrict__ C,
    const int M, const int N, const int K)
{
    __shared__ float As[BK][BM + 4];
    __shared__ float Bs[BK][BN + 4];
    const int tid = threadIdx.x;
    const int tx = tid & 15;
    const int ty = tid >> 4;
    const int m0 = blockIdx.y * BM;
    const int n0 = blockIdx.x * BN;
    const int ldr = tid >> 2;
    const int ldc = (tid & 3) << 2;

    float acc[4][4] = {};

    for (int k0 = 0; k0 < K; k0 += BK) {
        __syncthreads();
        const float4 av = *(const float4*)&A[(size_t)(m0 + ldr) * K + (k0 + ldc)];
        const float4 wv = *(const float4*)&W[(size_t)(n0 + ldr) * K + (k0 + ldc)];
        As[ldc + 0][ldr] = av.x; As[ldc + 1][ldr] = av.y;
        As[ldc + 2][ldr] = av.z; As[ldc + 3][ldr] = av.w;
        Bs[ldc + 0][ldr] = wv.x; Bs[ldc + 1][ldr] = wv.y;
        Bs[ldc + 2][ldr] = wv.z; Bs[ldc + 3][ldr] = wv.w;
        __syncthreads();
#pragma unroll
        for (int k = 0; k < BK; ++k) {
            const float4 a4 = *(const float4*)&As[k][ty << 2];
            const float4 b4 = *(const float4*)&Bs[k][tx << 2];
            const float aa[4] = {a4.x, a4.y, a4.z, a4.w};
            const float bb[4] = {b4.x, b4.y, b4.z, b4.w};
#pragma unroll
            for (int i = 0; i < 4; ++i)
#pragma unroll
                for (int j = 0; j < 4; ++j)
                    acc[i][j] = fmaf(aa[i], bb[j], acc[i][j]);
        }
    }

#pragma unroll
    for (int i = 0; i < 4; ++i) {
        const int row = m0 + (ty << 2) + i;
        const int col = n0 + (tx << 2);
        float4 ov;
        ov.x = acc[i][0]; ov.y = acc[i][1]; ov.z = acc[i][2]; ov.w = acc[i][3];
        if (bias != nullptr) {
            ov.x += bias[col + 0]; ov.y += bias[col + 1];
            ov.z += bias[col + 2]; ov.w += bias[col + 3];
        }
        *(float4*)&C[(size_t)row * N + col] = ov;
    }
}

// ============================================ RMS + RoPE (fp32 in, bf16 out)
__global__ __launch_bounds__(256) void rmsnorm_rope_bf16_kernel(
    const float* __restrict__ T, const float* __restrict__ g,
    const float* __restrict__ freqs, ushort_t* __restrict__ out)
{
    const int r = blockIdx.x;
    const int s = r & (SEQ - 1);
    const int tid = threadIdx.x;
    const int base = tid << 3;

    float v[8];
    *(float4*)&v[0] = *(const float4*)&T[(size_t)r * DIM + base];
    *(float4*)&v[4] = *(const float4*)&T[(size_t)r * DIM + base + 4];

    float ss = 0.f;
#pragma unroll
    for (int i = 0; i < 8; ++i) ss += v[i] * v[i];
#pragma unroll
    for (int off = 32; off > 0; off >>= 1) ss += __shfl_down(ss, off);

    __shared__ float wsum[4];
    __shared__ float inv_sh;
    if ((tid & 63) == 0) wsum[tid >> 6] = ss;
    __syncthreads();
    if (tid == 0)
        inv_sh = rsqrtf((wsum[0] + wsum[1] + wsum[2] + wsum[3]) * (1.0f / DIM) + EPS_RMS);
    __syncthreads();
    const float inv = inv_sh;

    float gg[8];
    *(float4*)&gg[0] = *(const float4*)&g[base];
    *(float4*)&gg[4] = *(const float4*)&g[base + 4];
#pragma unroll
    for (int i = 0; i < 8; ++i) v[i] *= inv * gg[i];

    const int p0 = (base & (HD - 1)) >> 1;
#pragma unroll
    for (int pp = 0; pp < 4; ++pp) {
        float sn, cs;
        __sincosf(freqs[(size_t)s * (HD / 2) + p0 + pp], &sn, &cs);
        const float t0 = v[2 * pp], t1 = v[2 * pp + 1];
        v[2 * pp]     = t0 * cs - t1 * sn;
        v[2 * pp + 1] = t0 * sn + t1 * cs;
    }

    uint_t pk[4];
#pragma unroll
    for (int j = 0; j < 4; ++j)
        pk[j] = (uint_t)f2bf(v[2 * j]) | ((uint_t)f2bf(v[2 * j + 1]) << 16);
    *(uint4*)&out[(size_t)r * DIM + base] = make_uint4(pk[0], pk[1], pk[2], pk[3]);
}

// ================================== RMS + RoPE (fp32 in/out, fallback path)
__global__ __launch_bounds__(256) void rmsnorm_rope_kernel(
    float* __restrict__ T, const float* __restrict__ g,
    const float* __restrict__ freqs)
{
    const int r = blockIdx.x;
    const int s = r & (SEQ - 1);
    const int tid = threadIdx.x;
    const int base = tid << 3;

    float v[8];
    *(float4*)&v[0] = *(const float4*)&T[(size_t)r * DIM + base];
    *(float4*)&v[4] = *(const float4*)&T[(size_t)r * DIM + base + 4];

    float ss = 0.f;
#pragma unroll
    for (int i = 0; i < 8; ++i) ss += v[i] * v[i];
#pragma unroll
    for (int off = 32; off > 0; off >>= 1) ss += __shfl_down(ss, off);

    __shared__ float wsum[4];
    __shared__ float inv_sh;
    if ((tid & 63) == 0) wsum[tid >> 6] = ss;
    __syncthreads();
    if (tid == 0)
        inv_sh = rsqrtf((wsum[0] + wsum[1] + wsum[2] + wsum[3]) * (1.0f / DIM) + EPS_RMS);
    __syncthreads();
    const float inv = inv_sh;

    float gg[8];
    *(float4*)&gg[0] = *(const float4*)&g[base];
    *(float4*)&gg[4] = *(const float4*)&g[base + 4];
#pragma unroll
    for (int i = 0; i < 8; ++i) v[i] *= inv * gg[i];

    const int p0 = (base & (HD - 1)) >> 1;
#pragma unroll
    for (int pp = 0; pp < 4; ++pp) {
        float sn, cs;
        __sincosf(freqs[(size_t)s * (HD / 2) + p0 + pp], &sn, &cs);
        const float t0 = v[2 * pp], t1 = v[2 * pp + 1];
        v[2 * pp]     = t0 * cs - t1 * sn;
        v[2 * pp + 1] = t0 * sn + t1 * cs;
    }

    *(float4*)&T[(size_t)r * DIM + base]     = *(float4*)&v[0];
    *(float4*)&T[(size_t)r * DIM + base + 4] = *(float4*)&v[4];
}

// ===================== V fp32 [tok][dim] -> bf16 Vt [b,h,d,s] (reg transpose)
// block: 128 d x 32 toks of one head. 4x4 in-register transpose, 8B stores.
__global__ __launch_bounds__(256) void vtrans_kernel(
    const float* __restrict__ V, ushort_t* __restrict__ Vt)
{
    const int t = threadIdx.x;
    const int h = blockIdx.y, b = blockIdx.z;
    const int dc   = (t & 31) << 2;               // 0..124
    const int tok0 = blockIdx.x * 32 + ((t >> 5) << 2);

    float4 rr[4];
#pragma unroll
    for (int j = 0; j < 4; ++j)
        rr[j] = *(const float4*)&V[(size_t)(b * SEQ + tok0 + j) * DIM + h * HD + dc];

#pragma unroll
    for (int j2 = 0; j2 < 4; ++j2) {
        const float e0 = ((const float*)&rr[0])[j2];
        const float e1 = ((const float*)&rr[1])[j2];
        const float e2 = ((const float*)&rr[2])[j2];
        const float e3 = ((const float*)&rr[3])[j2];
        uint2 pk;
        pk.x = (uint_t)f2bf(e0) | ((uint_t)f2bf(e1) << 16);
        pk.y = (uint_t)f2bf(e2) | ((uint_t)f2bf(e3) << 16);
        *(uint2*)&Vt[((size_t)(b * NH + h) * HD + dc + j2) * SEQ + tok0] = pk;
    }
}

// ======================================================== MFMA flash attention
// 128 queries/block, 4 waves x 32 queries, 64-key tiles.
// S^T = K·Q^T (C: row=key, col=query) -> softmax in-register -> P[q][k] LDS
// -> O += P·Vt. fp32 accum, bf16 operands.
#define AQ 128
#define AK 64
#define KSTR 136   // sK row stride (elems): 272 B, 16B-aligned
#define VSTR 72    // sVt/sP row stride (elems): 144 B, 16B-aligned

__global__ __launch_bounds__(256, 2) void attn_mfma_kernel(
    const ushort_t* __restrict__ QH, const ushort_t* __restrict__ KH,
    const ushort_t* __restrict__ VtG, const int* __restrict__ seq_lens,
    float* __restrict__ O)
{
    __shared__ __align__(16) ushort_t sK[AK * KSTR];    // [key][hd]
    __shared__ __align__(16) ushort_t sVt[HD * VSTR];   // [d][key]
    __shared__ __align__(16) ushort_t sP[AQ * VSTR];    // [query][key]

    const int tid  = threadIdx.x;
    const int w    = tid >> 6;
    const int lane = tid & 63;
    const int fr   = lane & 15;
    const int quad = lane >> 4;
    const int q0   = blockIdx.x * AQ;
    const int h    = blockIdx.y;
    const int b    = blockIdx.z;
    const int len  = seq_lens[b];
    const float scale = 0.088388347648318447f;  // 128^-0.5

    // ---- Q fragments in registers (bf16), B-operand layout
    bf16x8 qfrag[2][4];
#pragma unroll
    for (int qt = 0; qt < 2; ++qt)
#pragma unroll
        for (int h4 = 0; h4 < 4; ++h4) {
            const size_t qrow = (size_t)(b * SEQ + q0 + (w << 5) + (qt << 4) + fr);
            qfrag[qt][h4] = *(const bf16x8*)&QH[qrow * DIM + h * HD + (h4 << 5) + (quad << 3)];
        }

    f32x4 Oacc[2][8];
#pragma unroll
    for (int qt = 0; qt < 2; ++qt)
#pragma unroll
        for (int dt = 0; dt < 8; ++dt)
            Oacc[qt][dt] = (f32x4){0.f, 0.f, 0.f, 0.f};
    float mrow[2] = {-1.0e30f, -1.0e30f};
    float lrow[2] = {0.f, 0.f};

    const int ntiles = (len + AK - 1) / AK;
    for (int t = 0; t < ntiles; ++t) {
        const int k0 = t * AK;
        __syncthreads();
        // ---- stage K tile [64][128]
        for (int i = tid; i < AK * 16; i += 256) {
            const int key = i >> 4, c8 = (i & 15) << 3;
            const uint4 kv = *(const uint4*)&KH[(size_t)(b * SEQ + k0 + key) * DIM + h * HD + c8];
            *(uint4*)&sK[key * KSTR + c8] = kv;
        }
        // ---- stage Vt tile [128][64]
        for (int i = tid; i < HD * 8; i += 256) {
            const int d = i >> 3, kc = (i & 7) << 3;
            const uint4 vv = *(const uint4*)&VtG[((size_t)(b * NH + h) * HD + d) * SEQ + k0 + kc];
            *(uint4*)&sVt[d * VSTR + kc] = vv;
        }
        __syncthreads();

        // ---- scores S^T[key][query]
        f32x4 S[4][2];
#pragma unroll
        for (int kt = 0; kt < 4; ++kt) {
            bf16x8 kf[4];
#pragma unroll
            for (int h4 = 0; h4 < 4; ++h4)
                kf[h4] = *(const bf16x8*)&sK[((kt << 4) + fr) * KSTR + (h4 << 5) + (quad << 3)];
#pragma unroll
            for (int qt = 0; qt < 2; ++qt) {
                f32x4 a = (f32x4){0.f, 0.f, 0.f, 0.f};
#pragma unroll
                for (int h4 = 0; h4 < 4; ++h4)
                    a = __builtin_amdgcn_mfma_f32_16x16x32_bf16(kf[h4], qfrag[qt][h4], a, 0, 0, 0);
                S[kt][qt] = a;
            }
        }

        // ---- online softmax per query-16-tile (query = lane&15, replicated over quads)
#pragma unroll
        for (int qt = 0; qt < 2; ++qt) {
            float tm = -1.0e30f;
#pragma unroll
            for (int kt = 0; kt < 4; ++kt)
#pragma unroll
                for (int r = 0; r < 4; ++r) {
                    const int key = k0 + (kt << 4) + (quad << 2) + r;
                    float s = S[kt][qt][r] * scale;
                    s = (key < len) ? s : -1.0e30f;
                    S[kt][qt][r] = s;
                    tm = fmaxf(tm, s);
                }
            tm = fmaxf(tm, __shfl_xor(tm, 16));
            tm = fmaxf(tm, __shfl_xor(tm, 32));
            const float mnew = fmaxf(mrow[qt], tm);
            const float alpha = __expf(mrow[qt] - mnew);
            mrow[qt] = mnew;
            float rsum = 0.f;
#pragma unroll
            for (int kt = 0; kt < 4; ++kt) {
                float p[4];
#pragma unroll
                for (int r = 0; r < 4; ++r) {
                    p[r] = __expf(S[kt][qt][r] - mnew);
                    rsum += p[r];
                }
                uint2 pk;
                pk.x = (uint_t)f2bf(p[0]) | ((uint_t)f2bf(p[1]) << 16);
                pk.y = (uint_t)f2bf(p[2]) | ((uint_t)f2bf(p[3]) << 16);
                *(uint2*)&sP[((w << 5) + (qt << 4) + fr) * VSTR + (kt << 4) + (quad << 2)] = pk;
            }
            rsum += __shfl_xor(rsum, 16);
            rsum += __shfl_xor(rsum, 32);
            lrow[qt] = lrow[qt] * alpha + rsum;
            // rescale O by alpha (alpha indexed by query=lane&15 -> need quad*4+r)
#pragma unroll
            for (int r = 0; r < 4; ++r) {
                const float ar = __shfl(alpha, (quad << 2) + r);
#pragma unroll
                for (int dt = 0; dt < 8; ++dt)
                    Oacc[qt][dt][r] *= ar;
            }
        }

        // ---- PV: O += P·V  (A=P rows, B=Vt rows)
#pragma unroll
        for (int ks = 0; ks < 2; ++ks) {
            bf16x8 pf[2];
#pragma unroll
            for (int qt = 0; qt < 2; ++qt)
                pf[qt] = *(const bf16x8*)&sP[((w << 5) + (qt << 4) + fr) * VSTR + (ks << 5) + (quad << 3)];
#pragma unroll
            for (int dt = 0; dt < 8; ++dt) {
                const bf16x8 vf = *(const bf16x8*)&sVt[((dt << 4) + fr) * VSTR + (ks << 5) + (quad << 3)];
#pragma unroll
                for (int qt = 0; qt < 2; ++qt)
                    Oacc[qt][dt] = __builtin_amdgcn_mfma_f32_16x16x32_bf16(pf[qt], vf, Oacc[qt][dt], 0, 0, 0);
            }
        }
    }

    // ---- writeout (fp32)
#pragma unroll
    for (int qt = 0; qt < 2; ++qt) {
        float linv[4];
#pragma unroll
        for (int r = 0; r < 4; ++r)
            linv[r] = 1.0f / __shfl(lrow[qt], (quad << 2) + r);
#pragma unroll
        for (int dt = 0; dt < 8; ++dt)
#pragma unroll
            for (int r = 0; r < 4; ++r) {
                const int qrow = q0 + (w << 5) + (qt << 4) + (quad << 2) + r;
                O[(size_t)(b * SEQ + qrow) * DIM + h * HD + (dt << 4) + fr] =
                    Oacc[qt][dt][r] * linv[r];
            }
    }
}

// ======================================== fp32 flash attention (fallback)
#define BQ  64
#define BKT 64

__global__ __launch_bounds__(256) void attn_kernel(
    const float* __restrict__ Q, const float* __restrict__ K,
    const float* __restrict__ V, const int* __restrict__ seq_lens,
    float* __restrict__ O)
{
    const int qt = blockIdx.x;
    const int h  = blockIdx.y;
    const int b  = blockIdx.z;
    const int len = seq_lens[b];
    const int q0 = qt * BQ;
    const float scale = 0.088388347648318447f;

    __shared__ float Qst[HD][BQ + 4];
    __shared__ float Kst[HD][BKT + 4];
    __shared__ float Vs[BKT][HD + 4];
    __shared__ float Sc[BQ][BKT + 1];
    __shared__ float mrow[BQ], lrow[BQ], alpha_s[BQ];

    const int tid = threadIdx.x;
    const int si0 = (tid >> 4) << 2;
    const int sj0 = (tid & 15) << 2;
    const int pi0 = (tid >> 4) << 2;
    const int pc0 = (tid & 15) << 3;

    for (int i = tid; i < BQ * HD / 4; i += 256) {
        const int e = i << 2;
        const int row = e >> 7;
        const int c0 = e & (HD - 1);
        const float4 qv = *(const float4*)&Q[(size_t)(b * SEQ + q0 + row) * DIM + h * HD + c0];
        Qst[c0 + 0][row] = qv.x; Qst[c0 + 1][row] = qv.y;
        Qst[c0 + 2][row] = qv.z; Qst[c0 + 3][row] = qv.w;
    }
    if (tid < BQ) { mrow[tid] = -3.0e38f; lrow[tid] = 0.f; }

    float o[4][8] = {};
    __syncthreads();

    const int ntiles = (len + BKT - 1) / BKT;
    for (int t = 0; t < ntiles; ++t) {
        const int k0 = t * BKT;
        __syncthreads();
        for (int i = tid; i < BKT * HD / 4; i += 256) {
            const int e = i << 2;
            const int row = e >> 7;
            const int c0 = e & (HD - 1);
            const int kg = k0 + row;
            float4 kv = make_float4(0.f, 0.f, 0.f, 0.f);
            float4 vv = make_float4(0.f, 0.f, 0.f, 0.f);
            if (kg < len) {
                kv = *(const float4*)&K[(size_t)(b * SEQ + kg) * DIM + h * HD + c0];
                vv = *(const float4*)&V[(size_t)(b * SEQ + kg) * DIM + h * HD + c0];
            }
            Kst[c0 + 0][row] = kv.x; Kst[c0 + 1][row] = kv.y;
            Kst[c0 + 2][row] = kv.z; Kst[c0 + 3][row] = kv.w;
            *(float4*)&Vs[row][c0] = vv;
        }
        __syncthreads();

        float acc[4][4] = {};
#pragma unroll 8
        for (int kk = 0; kk < HD; ++kk) {
            const float4 q4 = *(const float4*)&Qst[kk][si0];
            const float4 k4 = *(const float4*)&Kst[kk][sj0];
            const float qa[4] = {q4.x, q4.y, q4.z, q4.w};
            const float ka[4] = {k4.x, k4.y, k4.z, k4.w};
#pragma unroll
            for (int i = 0; i < 4; ++i)
#pragma unroll
                for (int j = 0; j < 4; ++j)
                    acc[i][j] = fmaf(qa[i], ka[j], acc[i][j]);
        }
#pragma unroll
        for (int i = 0; i < 4; ++i)
#pragma unroll
            for (int j = 0; j < 4; ++j) {
                const int jg = k0 + sj0 + j;
                Sc[si0 + i][sj0 + j] = (jg < len) ? acc[i][j] * scale : -1.0e9f;
            }
        __syncthreads();

        if (tid < BQ) {
            const int i = tid;
            const float m_old = mrow[i];
            float mx = m_old;
            for (int j = 0; j < BKT; ++j) mx = fmaxf(mx, Sc[i][j]);
            const float al = __expf(m_old - mx);
            float sum = 0.f;
            for (int j = 0; j < BKT; ++j) {
                const float p = __expf(Sc[i][j] - mx);
                Sc[i][j] = p;
                sum += p;
            }
            mrow[i] = mx;
            lrow[i] = lrow[i] * al + sum;
            alpha_s[i] = al;
        }
        __syncthreads();

#pragma unroll
        for (int i = 0; i < 4; ++i) {
            const float al = alpha_s[pi0 + i];
#pragma unroll
            for (int c = 0; c < 8; ++c) o[i][c] *= al;
        }
        for (int j = 0; j < BKT; ++j) {
            float p[4];
#pragma unroll
            for (int i = 0; i < 4; ++i) p[i] = Sc[pi0 + i][j];
            const float4 v0 = *(const float4*)&Vs[j][pc0];
            const float4 v1 = *(const float4*)&Vs[j][pc0 + 4];
            const float va[8] = {v0.x, v0.y, v0.z, v0.w, v1.x, v1.y, v1.z, v1.w};
#pragma unroll
            for (int i = 0; i < 4; ++i)
#pragma unroll
                for (int c = 0; c < 8; ++c)
                    o[i][c] = fmaf(p[i], va[c], o[i][c]);
        }
    }

#pragma unroll
    for (int i = 0; i < 4; ++i) {
        const float invl = 1.0f / lrow[pi0 + i];
        float4 w0, w1;
        w0.x = o[i][0] * invl; w0.y = o[i][1] * invl;
        w0.z = o[i][2] * invl; w0.w = o[i][3] * invl;
        w1.x = o[i][4] * invl; w1.y = o[i][5] * invl;
        w1.z = o[i][6] * invl; w1.w = o[i][7] * invl;
        float* op = &O[(size_t)(b * SEQ + q0 + pi0 + i) * DIM + h * HD + pc0];
        *(float4*)&op[0] = w0;
        *(float4*)&op[4] = w1;
    }
}

// ==================================================================== launch
extern "C" void kernel_launch(void* const* d_in, const int* in_sizes, int n_in,
                              void* d_out, int out_size, void* d_ws, size_t ws_size,
                              hipStream_t stream)
{
    const float* x        = (const float*)d_in[0];
    const int*   seq_lens = (const int*)d_in[1];
    const float* freqs    = (const float*)d_in[3];
    const float* Wq       = (const float*)d_in[4];
    const float* Wk       = (const float*)d_in[5];
    const float* Wv       = (const float*)d_in[6];
    const float* Wo       = (const float*)d_in[7];
    const float* bo       = (const float*)d_in[8];
    const float* gq       = (const float*)d_in[9];
    const float* gk       = (const float*)d_in[10];
    float* out = (float*)d_out;

    const size_t mat = (size_t)NROWS * DIM;       // 8.39M elems
    const size_t wsz = (size_t)DIM * DIM;         // 4.19M elems

    float* Qb = (float*)d_ws;
    float* Kb = Qb + mat;
    float* Vb = Kb + mat;
    float* Ab = Vb + mat;

    ushort_t* xh  = (ushort_t*)(Ab + mat);
    ushort_t* xl  = xh + mat;
    ushort_t* wqh = xl + mat;
    ushort_t* wql = wqh + wsz;
    ushort_t* wkh = wql + wsz;
    ushort_t* wkl = wkh + wsz;
    ushort_t* wvh = wkl + wsz;
    ushort_t* wvl = wvh + wsz;
    ushort_t* woh = wvl + wsz;
    ushort_t* wol = woh + wsz;
    // bf16 attention operands
    ushort_t* qbh = wol + wsz;
    ushort_t* kbh = qbh + mat;
    ushort_t* vtg = kbh + mat;

    const size_t need2 = (4 * mat) * sizeof(float)
                       + (2 * mat + 8 * wsz) * sizeof(ushort_t);
    const size_t need3 = need2 + 3 * mat * sizeof(ushort_t);

    if (ws_size >= need3) {
        // ================= full MFMA path =================
        split_bf16_kernel<<<(int)(mat / (256 * 8)), 256, 0, stream>>>(x, xh, xl, (int)mat);
        split_bf16_kernel<<<(int)(wsz / (256 * 8)), 256, 0, stream>>>(Wq, wqh, wql, (int)wsz);
        split_bf16_kernel<<<(int)(wsz / (256 * 8)), 256, 0, stream>>>(Wk, wkh, wkl, (int)wsz);
        split_bf16_kernel<<<(int)(wsz / (256 * 8)), 256, 0, stream>>>(Wv, wvh, wvl, (int)wsz);
        split_bf16_kernel<<<(int)(wsz / (256 * 8)), 256, 0, stream>>>(Wo, woh, wol, (int)wsz);

        const dim3 gg(DIM / 128, NROWS / 128);
        gemm_bf16x3_kernel<<<gg, 256, 0, stream>>>(xh, xl, wqh, wql, nullptr, Qb, NROWS, DIM, DIM);
        gemm_bf16x3_kernel<<<gg, 256, 0, stream>>>(xh, xl, wkh, wkl, nullptr, Kb, NROWS, DIM, DIM);
        gemm_bf16x3_kernel<<<gg, 256, 0, stream>>>(xh, xl, wvh, wvl, nullptr, Vb, NROWS, DIM, DIM);

        rmsnorm_rope_bf16_kernel<<<NROWS, 256, 0, stream>>>(Qb, gq, freqs, qbh);
        rmsnorm_rope_bf16_kernel<<<NROWS, 256, 0, stream>>>(Kb, gk, freqs, kbh);
        vtrans_kernel<<<dim3(SEQ / 32, NH, BATCH), 256, 0, stream>>>(Vb, vtg);

        attn_mfma_kernel<<<dim3(SEQ / AQ, NH, BATCH), 256, 0, stream>>>(qbh, kbh, vtg, seq_lens, Ab);

        split_bf16_kernel<<<(int)(mat / (256 * 8)), 256, 0, stream>>>(Ab, xh, xl, (int)mat);
        gemm_bf16x3_kernel<<<gg, 256, 0, stream>>>(xh, xl, woh, wol, bo, out, NROWS, DIM, DIM);
    } else if (ws_size >= need2) {
        // ================= round-2 path (fp32 attention) =================
        split_bf16_kernel<<<(int)(mat / (256 * 8)), 256, 0, stream>>>(x, xh, xl, (int)mat);
        split_bf16_kernel<<<(int)(wsz / (256 * 8)), 256, 0, stream>>>(Wq, wqh, wql, (int)wsz);
        split_bf16_kernel<<<(int)(wsz / (256 * 8)), 256, 0, stream>>>(Wk, wkh, wkl, (int)wsz);
        split_bf16_kernel<<<(int)(wsz / (256 * 8)), 256, 0, stream>>>(Wv, wvh, wvl, (int)wsz);
        split_bf16_kernel<<<(int)(wsz / (256 * 8)), 256, 0, stream>>>(Wo, woh, wol, (int)wsz);

        const dim3 gg(DIM / 128, NROWS / 128);
        gemm_bf16x3_kernel<<<gg, 256, 0, stream>>>(xh, xl, wqh, wql, nullptr, Qb, NROWS, DIM, DIM);
        gemm_bf16x3_kernel<<<gg, 256, 0, stream>>>(xh, xl, wkh, wkl, nullptr, Kb, NROWS, DIM, DIM);
        gemm_bf16x3_kernel<<<gg, 256, 0, stream>>>(xh, xl, wvh, wvl, nullptr, Vb, NROWS, DIM, DIM);

        rmsnorm_rope_kernel<<<NROWS, 256, 0, stream>>>(Qb, gq, freqs);
        rmsnorm_rope_kernel<<<NROWS, 256, 0, stream>>>(Kb, gk, freqs);

        attn_kernel<<<dim3(SEQ / BQ, NH, BATCH), 256, 0, stream>>>(Qb, Kb, Vb, seq_lens, Ab);

        split_bf16_kernel<<<(int)(mat / (256 * 8)), 256, 0, stream>>>(Ab, xh, xl, (int)mat);
        gemm_bf16x3_kernel<<<gg, 256, 0, stream>>>(xh, xl, woh, wol, bo, out, NROWS, DIM, DIM);
    } else {
        // ================= fp32 fallback =================
        const dim3 gemm_grid(DIM / BN, NROWS / BM);
        gemm_nt_kernel<<<gemm_grid, 256, 0, stream>>>(x, Wq, nullptr, Qb, NROWS, DIM, DIM);
        gemm_nt_kernel<<<gemm_grid, 256, 0, stream>>>(x, Wk, nullptr, Kb, NROWS, DIM, DIM);
        gemm_nt_kernel<<<gemm_grid, 256, 0, stream>>>(x, Wv, nullptr, Vb, NROWS, DIM, DIM);
        rmsnorm_rope_kernel<<<NROWS, 256, 0, stream>>>(Qb, gq, freqs);
        rmsnorm_rope_kernel<<<NROWS, 256, 0, stream>>>(Kb, gk, freqs);
        attn_kernel<<<dim3(SEQ / BQ, NH, BATCH), 256, 0, stream>>>(Qb, Kb, Vb, seq_lens, Ab);
        gemm_nt_kernel<<<gemm_grid, 256, 0, stream>>>(Ab, Wo, bo, out, NROWS, DIM, DIM);
    }
}

// Round 4
// 751.522 us; speedup vs baseline: 4.5759x; 2.6366x over previous
//
#include <hip/hip_runtime.h>
#include <hip/hip_bf16.h>
#include <math.h>

#define BATCH 2
#define SEQ   2048
#define DIM   2048
#define NH    16
#define HD    128
#define NROWS (BATCH * SEQ)   // 4096
#define EPS_RMS 1e-6f

typedef unsigned short ushort_t;
typedef unsigned int   uint_t;
typedef __bf16 bf16x8 __attribute__((ext_vector_type(8)));
typedef float  f32x4  __attribute__((ext_vector_type(4)));

// ======================================================= fp32 -> bf16 (RNE)
__device__ inline ushort_t f2bf(float f) {
    uint_t u = __builtin_bit_cast(uint_t, f);
    uint_t r = u + 0x7FFFu + ((u >> 16) & 1u);
    return (ushort_t)(r >> 16);
}

// 8 floats per thread -> 8 hi bf16 + 8 lo bf16
__global__ __launch_bounds__(256) void split_bf16_kernel(
    const float* __restrict__ src, ushort_t* __restrict__ hi,
    ushort_t* __restrict__ lo, const int n)
{
    const int i = (blockIdx.x * 256 + threadIdx.x) << 3;
    if (i >= n) return;
    float v[8];
    *(float4*)&v[0] = *(const float4*)&src[i];
    *(float4*)&v[4] = *(const float4*)&src[i + 4];
    uint_t hp[4], lp[4];
#pragma unroll
    for (int j = 0; j < 4; ++j) {
        ushort_t h0 = f2bf(v[2 * j]);
        ushort_t h1 = f2bf(v[2 * j + 1]);
        float h0f = __builtin_bit_cast(float, (uint_t)h0 << 16);
        float h1f = __builtin_bit_cast(float, (uint_t)h1 << 16);
        ushort_t l0 = f2bf(v[2 * j] - h0f);
        ushort_t l1 = f2bf(v[2 * j + 1] - h1f);
        hp[j] = (uint_t)h0 | ((uint_t)h1 << 16);
        lp[j] = (uint_t)l0 | ((uint_t)l1 << 16);
    }
    *(uint4*)&hi[i] = make_uint4(hp[0], hp[1], hp[2], hp[3]);
    *(uint4*)&lo[i] = make_uint4(lp[0], lp[1], lp[2], lp[3]);
}

// ============================================= split-bf16 MFMA GEMM (3-term)
__global__ __launch_bounds__(256, 2) void gemm_bf16x3_kernel(
    const ushort_t* __restrict__ Ah, const ushort_t* __restrict__ Al,
    const ushort_t* __restrict__ Bh, const ushort_t* __restrict__ Bl,
    const float* __restrict__ bias, float* __restrict__ C,
    const int M, const int N, const int K)
{
    __shared__ __align__(16) ushort_t sAh[4096], sAl[4096], sBh[4096], sBl[4096];
    const int tid  = threadIdx.x;
    const int w    = tid >> 6;
    const int lane = tid & 63;
    const int m0 = blockIdx.y * 128;
    const int n0 = blockIdx.x * 128;

    const int scol = (lane & 3) << 3;
    const int wr = w >> 1, wc = w & 1;
    const int fr = lane & 15, quad = lane >> 4;

    f32x4 acc[4][4];
#pragma unroll
    for (int mi = 0; mi < 4; ++mi)
#pragma unroll
        for (int ni = 0; ni < 4; ++ni)
            acc[mi][ni] = (f32x4){0.f, 0.f, 0.f, 0.f};

    for (int k0 = 0; k0 < K; k0 += 32) {
        __syncthreads();
#pragma unroll
        for (int it = 0; it < 2; ++it) {
            const int row  = (w << 5) + (it << 4) + (lane >> 2);
            const int loff = (w << 10) + (it << 9);
            const size_t ga = (size_t)(m0 + row) * K + k0 + scol;
            const size_t gb = (size_t)(n0 + row) * K + k0 + scol;
            __builtin_amdgcn_global_load_lds(
                (const __attribute__((address_space(1))) uint_t*)(const void*)(Ah + ga),
                (__attribute__((address_space(3))) uint_t*)(void*)&sAh[loff], 16, 0, 0);
            __builtin_amdgcn_global_load_lds(
                (const __attribute__((address_space(1))) uint_t*)(const void*)(Al + ga),
                (__attribute__((address_space(3))) uint_t*)(void*)&sAl[loff], 16, 0, 0);
            __builtin_amdgcn_global_load_lds(
                (const __attribute__((address_space(1))) uint_t*)(const void*)(Bh + gb),
                (__attribute__((address_space(3))) uint_t*)(void*)&sBh[loff], 16, 0, 0);
            __builtin_amdgcn_global_load_lds(
                (const __attribute__((address_space(1))) uint_t*)(const void*)(Bl + gb),
                (__attribute__((address_space(3))) uint_t*)(void*)&sBl[loff], 16, 0, 0);
        }
        __syncthreads();

        bf16x8 bh[4], bl[4];
#pragma unroll
        for (int ni = 0; ni < 4; ++ni) {
            const int row = (wc << 6) + (ni << 4) + fr;
            bh[ni] = *(const bf16x8*)&sBh[(row << 5) + (quad << 3)];
            bl[ni] = *(const bf16x8*)&sBl[(row << 5) + (quad << 3)];
        }
#pragma unroll
        for (int mi = 0; mi < 4; ++mi) {
            const int row = (wr << 6) + (mi << 4) + fr;
            const bf16x8 ah = *(const bf16x8*)&sAh[(row << 5) + (quad << 3)];
            const bf16x8 al = *(const bf16x8*)&sAl[(row << 5) + (quad << 3)];
#pragma unroll
            for (int ni = 0; ni < 4; ++ni) {
                acc[mi][ni] = __builtin_amdgcn_mfma_f32_16x16x32_bf16(ah, bh[ni], acc[mi][ni], 0, 0, 0);
                acc[mi][ni] = __builtin_amdgcn_mfma_f32_16x16x32_bf16(ah, bl[ni], acc[mi][ni], 0, 0, 0);
                acc[mi][ni] = __builtin_amdgcn_mfma_f32_16x16x32_bf16(al, bh[ni], acc[mi][ni], 0, 0, 0);
            }
        }
    }

#pragma unroll
    for (int mi = 0; mi < 4; ++mi)
#pragma unroll
        for (int ni = 0; ni < 4; ++ni) {
            const int col = n0 + (wc << 6) + (ni << 4) + fr;
            const float bv = bias ? bias[col] : 0.f;
#pragma unroll
            for (int r = 0; r < 4; ++r) {
                const int rowg = m0 + (wr << 6) + (mi << 4) + (quad << 2) + r;
                C[(size_t)rowg * N + col] = acc[mi][ni][r] + bv;
            }
        }
}

// ===================================================================== GEMM (fp32 fallback)
#define BM 64
#define BN 64
#define BK 16

__global__ __launch_bounds__(256) void gemm_nt_kernel(
    const float* __restrict__ A, const float* __restrict__ W,
    const float* __restrict__ bias, float* __restrict__ C,
    const int M, const int N, const int K)
{
    __shared__ float As[BK][BM + 4];
    __shared__ float Bs[BK][BN + 4];
    const int tid = threadIdx.x;
    const int tx = tid & 15;
    const int ty = tid >> 4;
    const int m0 = blockIdx.y * BM;
    const int n0 = blockIdx.x * BN;
    const int ldr = tid >> 2;
    const int ldc = (tid & 3) << 2;

    float acc[4][4] = {};

    for (int k0 = 0; k0 < K; k0 += BK) {
        __syncthreads();
        const float4 av = *(const float4*)&A[(size_t)(m0 + ldr) * K + (k0 + ldc)];
        const float4 wv = *(const float4*)&W[(size_t)(n0 + ldr) * K + (k0 + ldc)];
        As[ldc + 0][ldr] = av.x; As[ldc + 1][ldr] = av.y;
        As[ldc + 2][ldr] = av.z; As[ldc + 3][ldr] = av.w;
        Bs[ldc + 0][ldr] = wv.x; Bs[ldc + 1][ldr] = wv.y;
        Bs[ldc + 2][ldr] = wv.z; Bs[ldc + 3][ldr] = wv.w;
        __syncthreads();
#pragma unroll
        for (int k = 0; k < BK; ++k) {
            const float4 a4 = *(const float4*)&As[k][ty << 2];
            const float4 b4 = *(const float4*)&Bs[k][tx << 2];
            const float aa[4] = {a4.x, a4.y, a4.z, a4.w};
            const float bb[4] = {b4.x, b4.y, b4.z, b4.w};
#pragma unroll
            for (int i = 0; i < 4; ++i)
#pragma unroll
                for (int j = 0; j < 4; ++j)
                    acc[i][j] = fmaf(aa[i], bb[j], acc[i][j]);
        }
    }

#pragma unroll
    for (int i = 0; i < 4; ++i) {
        const int row = m0 + (ty << 2) + i;
        const int col = n0 + (tx << 2);
        float4 ov;
        ov.x = acc[i][0]; ov.y = acc[i][1]; ov.z = acc[i][2]; ov.w = acc[i][3];
        if (bias != nullptr) {
            ov.x += bias[col + 0]; ov.y += bias[col + 1];
            ov.z += bias[col + 2]; ov.w += bias[col + 3];
        }
        *(float4*)&C[(size_t)row * N + col] = ov;
    }
}

// ============================================ RMS + RoPE (fp32 in, bf16 out)
__global__ __launch_bounds__(256) void rmsnorm_rope_bf16_kernel(
    const float* __restrict__ T, const float* __restrict__ g,
    const float* __restrict__ freqs, ushort_t* __restrict__ out)
{
    const int r = blockIdx.x;
    const int s = r & (SEQ - 1);
    const int tid = threadIdx.x;
    const int base = tid << 3;

    float v[8];
    *(float4*)&v[0] = *(const float4*)&T[(size_t)r * DIM + base];
    *(float4*)&v[4] = *(const float4*)&T[(size_t)r * DIM + base + 4];

    float ss = 0.f;
#pragma unroll
    for (int i = 0; i < 8; ++i) ss += v[i] * v[i];
#pragma unroll
    for (int off = 32; off > 0; off >>= 1) ss += __shfl_down(ss, off);

    __shared__ float wsum[4];
    __shared__ float inv_sh;
    if ((tid & 63) == 0) wsum[tid >> 6] = ss;
    __syncthreads();
    if (tid == 0)
        inv_sh = rsqrtf((wsum[0] + wsum[1] + wsum[2] + wsum[3]) * (1.0f / DIM) + EPS_RMS);
    __syncthreads();
    const float inv = inv_sh;

    float gg[8];
    *(float4*)&gg[0] = *(const float4*)&g[base];
    *(float4*)&gg[4] = *(const float4*)&g[base + 4];
#pragma unroll
    for (int i = 0; i < 8; ++i) v[i] *= inv * gg[i];

    const int p0 = (base & (HD - 1)) >> 1;
#pragma unroll
    for (int pp = 0; pp < 4; ++pp) {
        float sn, cs;
        __sincosf(freqs[(size_t)s * (HD / 2) + p0 + pp], &sn, &cs);
        const float t0 = v[2 * pp], t1 = v[2 * pp + 1];
        v[2 * pp]     = t0 * cs - t1 * sn;
        v[2 * pp + 1] = t0 * sn + t1 * cs;
    }

    uint_t pk[4];
#pragma unroll
    for (int j = 0; j < 4; ++j)
        pk[j] = (uint_t)f2bf(v[2 * j]) | ((uint_t)f2bf(v[2 * j + 1]) << 16);
    *(uint4*)&out[(size_t)r * DIM + base] = make_uint4(pk[0], pk[1], pk[2], pk[3]);
}

// ================================== RMS + RoPE (fp32 in/out, fallback path)
__global__ __launch_bounds__(256) void rmsnorm_rope_kernel(
    float* __restrict__ T, const float* __restrict__ g,
    const float* __restrict__ freqs)
{
    const int r = blockIdx.x;
    const int s = r & (SEQ - 1);
    const int tid = threadIdx.x;
    const int base = tid << 3;

    float v[8];
    *(float4*)&v[0] = *(const float4*)&T[(size_t)r * DIM + base];
    *(float4*)&v[4] = *(const float4*)&T[(size_t)r * DIM + base + 4];

    float ss = 0.f;
#pragma unroll
    for (int i = 0; i < 8; ++i) ss += v[i] * v[i];
#pragma unroll
    for (int off = 32; off > 0; off >>= 1) ss += __shfl_down(ss, off);

    __shared__ float wsum[4];
    __shared__ float inv_sh;
    if ((tid & 63) == 0) wsum[tid >> 6] = ss;
    __syncthreads();
    if (tid == 0)
        inv_sh = rsqrtf((wsum[0] + wsum[1] + wsum[2] + wsum[3]) * (1.0f / DIM) + EPS_RMS);
    __syncthreads();
    const float inv = inv_sh;

    float gg[8];
    *(float4*)&gg[0] = *(const float4*)&g[base];
    *(float4*)&gg[4] = *(const float4*)&g[base + 4];
#pragma unroll
    for (int i = 0; i < 8; ++i) v[i] *= inv * gg[i];

    const int p0 = (base & (HD - 1)) >> 1;
#pragma unroll
    for (int pp = 0; pp < 4; ++pp) {
        float sn, cs;
        __sincosf(freqs[(size_t)s * (HD / 2) + p0 + pp], &sn, &cs);
        const float t0 = v[2 * pp], t1 = v[2 * pp + 1];
        v[2 * pp]     = t0 * cs - t1 * sn;
        v[2 * pp + 1] = t0 * sn + t1 * cs;
    }

    *(float4*)&T[(size_t)r * DIM + base]     = *(float4*)&v[0];
    *(float4*)&T[(size_t)r * DIM + base + 4] = *(float4*)&v[4];
}

// ===================== V fp32 [tok][dim] -> bf16 Vt [b,h,d,s] (reg transpose)
__global__ __launch_bounds__(256) void vtrans_kernel(
    const float* __restrict__ V, ushort_t* __restrict__ Vt)
{
    const int t = threadIdx.x;
    const int h = blockIdx.y, b = blockIdx.z;
    const int dc   = (t & 31) << 2;               // 0..124
    const int tok0 = blockIdx.x * 32 + ((t >> 5) << 2);

    float4 rr[4];
#pragma unroll
    for (int j = 0; j < 4; ++j)
        rr[j] = *(const float4*)&V[(size_t)(b * SEQ + tok0 + j) * DIM + h * HD + dc];

#pragma unroll
    for (int j2 = 0; j2 < 4; ++j2) {
        const float e0 = ((const float*)&rr[0])[j2];
        const float e1 = ((const float*)&rr[1])[j2];
        const float e2 = ((const float*)&rr[2])[j2];
        const float e3 = ((const float*)&rr[3])[j2];
        uint2 pk;
        pk.x = (uint_t)f2bf(e0) | ((uint_t)f2bf(e1) << 16);
        pk.y = (uint_t)f2bf(e2) | ((uint_t)f2bf(e3) << 16);
        *(uint2*)&Vt[((size_t)(b * NH + h) * HD + dc + j2) * SEQ + tok0] = pk;
    }
}

// ======================================================== MFMA flash attention
// 128 queries/block, 4 waves x 32 queries, 64-key tiles.
// S^T = K·Q^T (C: row=key, col=query) -> softmax in-register -> P[q][k] LDS
// -> O += P·Vt. fp32 accum, bf16 operands.
#define AQ 128
#define AK 64
#define KSTR 136   // sK row stride (elems): 272 B, 16B-aligned
#define VSTR 72    // sVt/sP row stride (elems): 144 B, 16B-aligned

__global__ __launch_bounds__(256, 2) void attn_mfma_kernel(
    const ushort_t* __restrict__ QH, const ushort_t* __restrict__ KH,
    const ushort_t* __restrict__ VtG, const int* __restrict__ seq_lens,
    float* __restrict__ O)
{
    __shared__ __align__(16) ushort_t sK[AK * KSTR];    // [key][hd]
    __shared__ __align__(16) ushort_t sVt[HD * VSTR];   // [d][key]
    __shared__ __align__(16) ushort_t sP[AQ * VSTR];    // [query][key]

    const int tid  = threadIdx.x;
    const int w    = tid >> 6;
    const int lane = tid & 63;
    const int fr   = lane & 15;
    const int quad = lane >> 4;
    const int q0   = blockIdx.x * AQ;
    const int h    = blockIdx.y;
    const int b    = blockIdx.z;
    const int len  = seq_lens[b];
    const float scale = 0.088388347648318447f;  // 128^-0.5

    // ---- Q fragments in registers (bf16), B-operand layout
    bf16x8 qfrag[2][4];
#pragma unroll
    for (int qt = 0; qt < 2; ++qt)
#pragma unroll
        for (int h4 = 0; h4 < 4; ++h4) {
            const size_t qrow = (size_t)(b * SEQ + q0 + (w << 5) + (qt << 4) + fr);
            qfrag[qt][h4] = *(const bf16x8*)&QH[qrow * DIM + h * HD + (h4 << 5) + (quad << 3)];
        }

    f32x4 Oacc[2][8];
#pragma unroll
    for (int qt = 0; qt < 2; ++qt)
#pragma unroll
        for (int dt = 0; dt < 8; ++dt)
            Oacc[qt][dt] = (f32x4){0.f, 0.f, 0.f, 0.f};
    float mrow[2] = {-1.0e30f, -1.0e30f};
    float lrow[2] = {0.f, 0.f};

    const int ntiles = (len + AK - 1) / AK;
    for (int t = 0; t < ntiles; ++t) {
        const int k0 = t * AK;
        __syncthreads();
        // ---- stage K tile [64][128]
        for (int i = tid; i < AK * 16; i += 256) {
            const int key = i >> 4, c8 = (i & 15) << 3;
            const uint4 kv = *(const uint4*)&KH[(size_t)(b * SEQ + k0 + key) * DIM + h * HD + c8];
            *(uint4*)&sK[key * KSTR + c8] = kv;
        }
        // ---- stage Vt tile [128][64]
        for (int i = tid; i < HD * 8; i += 256) {
            const int d = i >> 3, kc = (i & 7) << 3;
            const uint4 vv = *(const uint4*)&VtG[((size_t)(b * NH + h) * HD + d) * SEQ + k0 + kc];
            *(uint4*)&sVt[d * VSTR + kc] = vv;
        }
        __syncthreads();

        // ---- scores S^T[key][query]
        f32x4 S[4][2];
#pragma unroll
        for (int kt = 0; kt < 4; ++kt) {
            bf16x8 kf[4];
#pragma unroll
            for (int h4 = 0; h4 < 4; ++h4)
                kf[h4] = *(const bf16x8*)&sK[((kt << 4) + fr) * KSTR + (h4 << 5) + (quad << 3)];
#pragma unroll
            for (int qt = 0; qt < 2; ++qt) {
                f32x4 a = (f32x4){0.f, 0.f, 0.f, 0.f};
#pragma unroll
                for (int h4 = 0; h4 < 4; ++h4)
                    a = __builtin_amdgcn_mfma_f32_16x16x32_bf16(kf[h4], qfrag[qt][h4], a, 0, 0, 0);
                S[kt][qt] = a;
            }
        }

        // ---- online softmax per query (query = lane&15, keys spread over quads)
#pragma unroll
        for (int qt = 0; qt < 2; ++qt) {
            float tm = -1.0e30f;
#pragma unroll
            for (int kt = 0; kt < 4; ++kt)
#pragma unroll
                for (int r = 0; r < 4; ++r) {
                    const int key = k0 + (kt << 4) + (quad << 2) + r;
                    float s = S[kt][qt][r] * scale;
                    s = (key < len) ? s : -1.0e30f;
                    S[kt][qt][r] = s;
                    tm = fmaxf(tm, s);
                }
            tm = fmaxf(tm, __shfl_xor(tm, 16));
            tm = fmaxf(tm, __shfl_xor(tm, 32));
            const float mnew = fmaxf(mrow[qt], tm);
            const float alpha = __expf(mrow[qt] - mnew);
            mrow[qt] = mnew;
            float rsum = 0.f;
#pragma unroll
            for (int kt = 0; kt < 4; ++kt) {
                float p[4];
#pragma unroll
                for (int r = 0; r < 4; ++r) {
                    p[r] = __expf(S[kt][qt][r] - mnew);
                    rsum += p[r];
                }
                uint2 pk;
                pk.x = (uint_t)f2bf(p[0]) | ((uint_t)f2bf(p[1]) << 16);
                pk.y = (uint_t)f2bf(p[2]) | ((uint_t)f2bf(p[3]) << 16);
                *(uint2*)&sP[((w << 5) + (qt << 4) + fr) * VSTR + (kt << 4) + (quad << 2)] = pk;
            }
            rsum += __shfl_xor(rsum, 16);
            rsum += __shfl_xor(rsum, 32);
            lrow[qt] = lrow[qt] * alpha + rsum;
#pragma unroll
            for (int r = 0; r < 4; ++r) {
                const float ar = __shfl(alpha, (quad << 2) + r);
#pragma unroll
                for (int dt = 0; dt < 8; ++dt)
                    Oacc[qt][dt][r] *= ar;
            }
        }

        // ---- PV: O += P·V  (A=P rows, B=Vt rows)
#pragma unroll
        for (int ks = 0; ks < 2; ++ks) {
            bf16x8 pf[2];
#pragma unroll
            for (int qt = 0; qt < 2; ++qt)
                pf[qt] = *(const bf16x8*)&sP[((w << 5) + (qt << 4) + fr) * VSTR + (ks << 5) + (quad << 3)];
#pragma unroll
            for (int dt = 0; dt < 8; ++dt) {
                const bf16x8 vf = *(const bf16x8*)&sVt[((dt << 4) + fr) * VSTR + (ks << 5) + (quad << 3)];
#pragma unroll
                for (int qt = 0; qt < 2; ++qt)
                    Oacc[qt][dt] = __builtin_amdgcn_mfma_f32_16x16x32_bf16(pf[qt], vf, Oacc[qt][dt], 0, 0, 0);
            }
        }
    }

    // ---- writeout (fp32)
#pragma unroll
    for (int qt = 0; qt < 2; ++qt) {
        float linv[4];
#pragma unroll
        for (int r = 0; r < 4; ++r)
            linv[r] = 1.0f / __shfl(lrow[qt], (quad << 2) + r);
#pragma unroll
        for (int dt = 0; dt < 8; ++dt)
#pragma unroll
            for (int r = 0; r < 4; ++r) {
                const int qrow = q0 + (w << 5) + (qt << 4) + (quad << 2) + r;
                O[(size_t)(b * SEQ + qrow) * DIM + h * HD + (dt << 4) + fr] =
                    Oacc[qt][dt][r] * linv[r];
            }
    }
}

// ======================================== fp32 flash attention (fallback)
#define BQ  64
#define BKT 64

__global__ __launch_bounds__(256) void attn_kernel(
    const float* __restrict__ Q, const float* __restrict__ K,
    const float* __restrict__ V, const int* __restrict__ seq_lens,
    float* __restrict__ O)
{
    const int qt = blockIdx.x;
    const int h  = blockIdx.y;
    const int b  = blockIdx.z;
    const int len = seq_lens[b];
    const int q0 = qt * BQ;
    const float scale = 0.088388347648318447f;

    __shared__ float Qst[HD][BQ + 4];
    __shared__ float Kst[HD][BKT + 4];
    __shared__ float Vs[BKT][HD + 4];
    __shared__ float Sc[BQ][BKT + 1];
    __shared__ float mrow[BQ], lrow[BQ], alpha_s[BQ];

    const int tid = threadIdx.x;
    const int si0 = (tid >> 4) << 2;
    const int sj0 = (tid & 15) << 2;
    const int pi0 = (tid >> 4) << 2;
    const int pc0 = (tid & 15) << 3;

    for (int i = tid; i < BQ * HD / 4; i += 256) {
        const int e = i << 2;
        const int row = e >> 7;
        const int c0 = e & (HD - 1);
        const float4 qv = *(const float4*)&Q[(size_t)(b * SEQ + q0 + row) * DIM + h * HD + c0];
        Qst[c0 + 0][row] = qv.x; Qst[c0 + 1][row] = qv.y;
        Qst[c0 + 2][row] = qv.z; Qst[c0 + 3][row] = qv.w;
    }
    if (tid < BQ) { mrow[tid] = -3.0e38f; lrow[tid] = 0.f; }

    float o[4][8] = {};
    __syncthreads();

    const int ntiles = (len + BKT - 1) / BKT;
    for (int t = 0; t < ntiles; ++t) {
        const int k0 = t * BKT;
        __syncthreads();
        for (int i = tid; i < BKT * HD / 4; i += 256) {
            const int e = i << 2;
            const int row = e >> 7;
            const int c0 = e & (HD - 1);
            const int kg = k0 + row;
            float4 kv = make_float4(0.f, 0.f, 0.f, 0.f);
            float4 vv = make_float4(0.f, 0.f, 0.f, 0.f);
            if (kg < len) {
                kv = *(const float4*)&K[(size_t)(b * SEQ + kg) * DIM + h * HD + c0];
                vv = *(const float4*)&V[(size_t)(b * SEQ + kg) * DIM + h * HD + c0];
            }
            Kst[c0 + 0][row] = kv.x; Kst[c0 + 1][row] = kv.y;
            Kst[c0 + 2][row] = kv.z; Kst[c0 + 3][row] = kv.w;
            *(float4*)&Vs[row][c0] = vv;
        }
        __syncthreads();

        float acc[4][4] = {};
#pragma unroll 8
        for (int kk = 0; kk < HD; ++kk) {
            const float4 q4 = *(const float4*)&Qst[kk][si0];
            const float4 k4 = *(const float4*)&Kst[kk][sj0];
            const float qa[4] = {q4.x, q4.y, q4.z, q4.w};
            const float ka[4] = {k4.x, k4.y, k4.z, k4.w};
#pragma unroll
            for (int i = 0; i < 4; ++i)
#pragma unroll
                for (int j = 0; j < 4; ++j)
                    acc[i][j] = fmaf(qa[i], ka[j], acc[i][j]);
        }
#pragma unroll
        for (int i = 0; i < 4; ++i)
#pragma unroll
            for (int j = 0; j < 4; ++j) {
                const int jg = k0 + sj0 + j;
                Sc[si0 + i][sj0 + j] = (jg < len) ? acc[i][j] * scale : -1.0e9f;
            }
        __syncthreads();

        if (tid < BQ) {
            const int i = tid;
            const float m_old = mrow[i];
            float mx = m_old;
            for (int j = 0; j < BKT; ++j) mx = fmaxf(mx, Sc[i][j]);
            const float al = __expf(m_old - mx);
            float sum = 0.f;
            for (int j = 0; j < BKT; ++j) {
                const float p = __expf(Sc[i][j] - mx);
                Sc[i][j] = p;
                sum += p;
            }
            mrow[i] = mx;
            lrow[i] = lrow[i] * al + sum;
            alpha_s[i] = al;
        }
        __syncthreads();

#pragma unroll
        for (int i = 0; i < 4; ++i) {
            const float al = alpha_s[pi0 + i];
#pragma unroll
            for (int c = 0; c < 8; ++c) o[i][c] *= al;
        }
        for (int j = 0; j < BKT; ++j) {
            float p[4];
#pragma unroll
            for (int i = 0; i < 4; ++i) p[i] = Sc[pi0 + i][j];
            const float4 v0 = *(const float4*)&Vs[j][pc0];
            const float4 v1 = *(const float4*)&Vs[j][pc0 + 4];
            const float va[8] = {v0.x, v0.y, v0.z, v0.w, v1.x, v1.y, v1.z, v1.w};
#pragma unroll
            for (int i = 0; i < 4; ++i)
#pragma unroll
                for (int c = 0; c < 8; ++c)
                    o[i][c] = fmaf(p[i], va[c], o[i][c]);
        }
    }

#pragma unroll
    for (int i = 0; i < 4; ++i) {
        const float invl = 1.0f / lrow[pi0 + i];
        float4 w0, w1;
        w0.x = o[i][0] * invl; w0.y = o[i][1] * invl;
        w0.z = o[i][2] * invl; w0.w = o[i][3] * invl;
        w1.x = o[i][4] * invl; w1.y = o[i][5] * invl;
        w1.z = o[i][6] * invl; w1.w = o[i][7] * invl;
        float* op = &O[(size_t)(b * SEQ + q0 + pi0 + i) * DIM + h * HD + pc0];
        *(float4*)&op[0] = w0;
        *(float4*)&op[4] = w1;
    }
}

// ==================================================================== launch
extern "C" void kernel_launch(void* const* d_in, const int* in_sizes, int n_in,
                              void* d_out, int out_size, void* d_ws, size_t ws_size,
                              hipStream_t stream)
{
    const float* x        = (const float*)d_in[0];
    const int*   seq_lens = (const int*)d_in[1];
    const float* freqs    = (const float*)d_in[3];
    const float* Wq       = (const float*)d_in[4];
    const float* Wk       = (const float*)d_in[5];
    const float* Wv       = (const float*)d_in[6];
    const float* Wo       = (const float*)d_in[7];
    const float* bo       = (const float*)d_in[8];
    const float* gq       = (const float*)d_in[9];
    const float* gk       = (const float*)d_in[10];
    float* out = (float*)d_out;

    const size_t mat = (size_t)NROWS * DIM;       // 8.39M elems
    const size_t wsz = (size_t)DIM * DIM;         // 4.19M elems  (mat == 2*wsz)

    float* Qb = (float*)d_ws;
    float* Kb = Qb + mat;
    float* Vb = Kb + mat;
    float* Ab = Vb + mat;

    ushort_t* xh  = (ushort_t*)(Ab + mat);
    ushort_t* xl  = xh + mat;
    ushort_t* wqh = xl + mat;
    ushort_t* wql = wqh + wsz;
    ushort_t* wkh = wql + wsz;
    ushort_t* wkl = wkh + wsz;
    ushort_t* wvh = wkl + wsz;
    ushort_t* wvl = wvh + wsz;
    ushort_t* woh = wvl + wsz;
    ushort_t* wol = woh + wsz;

    // bf16 attention operands ALIAS the QKV weight regions (dead after the
    // three QKV GEMMs; stream ordering serializes producer/consumer):
    //   qbh (mat elems) <- wqh+wql ; kbh <- wkh+wkl ; vtg <- wvh+wvl
    ushort_t* qbh = wqh;
    ushort_t* kbh = wkh;
    ushort_t* vtg = wvh;

    const size_t need2 = (4 * mat) * sizeof(float)
                       + (2 * mat + 8 * wsz) * sizeof(ushort_t);   // 224 MB

    if (ws_size >= need2) {
        // ================= full MFMA path =================
        split_bf16_kernel<<<(int)(mat / (256 * 8)), 256, 0, stream>>>(x, xh, xl, (int)mat);
        split_bf16_kernel<<<(int)(wsz / (256 * 8)), 256, 0, stream>>>(Wq, wqh, wql, (int)wsz);
        split_bf16_kernel<<<(int)(wsz / (256 * 8)), 256, 0, stream>>>(Wk, wkh, wkl, (int)wsz);
        split_bf16_kernel<<<(int)(wsz / (256 * 8)), 256, 0, stream>>>(Wv, wvh, wvl, (int)wsz);
        split_bf16_kernel<<<(int)(wsz / (256 * 8)), 256, 0, stream>>>(Wo, woh, wol, (int)wsz);

        const dim3 gg(DIM / 128, NROWS / 128);
        gemm_bf16x3_kernel<<<gg, 256, 0, stream>>>(xh, xl, wqh, wql, nullptr, Qb, NROWS, DIM, DIM);
        gemm_bf16x3_kernel<<<gg, 256, 0, stream>>>(xh, xl, wkh, wkl, nullptr, Kb, NROWS, DIM, DIM);
        gemm_bf16x3_kernel<<<gg, 256, 0, stream>>>(xh, xl, wvh, wvl, nullptr, Vb, NROWS, DIM, DIM);

        // overwrite dead weight regions with attention operands
        rmsnorm_rope_bf16_kernel<<<NROWS, 256, 0, stream>>>(Qb, gq, freqs, qbh);
        rmsnorm_rope_bf16_kernel<<<NROWS, 256, 0, stream>>>(Kb, gk, freqs, kbh);
        vtrans_kernel<<<dim3(SEQ / 32, NH, BATCH), 256, 0, stream>>>(Vb, vtg);

        attn_mfma_kernel<<<dim3(SEQ / AQ, NH, BATCH), 256, 0, stream>>>(qbh, kbh, vtg, seq_lens, Ab);

        split_bf16_kernel<<<(int)(mat / (256 * 8)), 256, 0, stream>>>(Ab, xh, xl, (int)mat);
        gemm_bf16x3_kernel<<<gg, 256, 0, stream>>>(xh, xl, woh, wol, bo, out, NROWS, DIM, DIM);
    } else {
        // ================= fp32 fallback =================
        const dim3 gemm_grid(DIM / BN, NROWS / BM);
        gemm_nt_kernel<<<gemm_grid, 256, 0, stream>>>(x, Wq, nullptr, Qb, NROWS, DIM, DIM);
        gemm_nt_kernel<<<gemm_grid, 256, 0, stream>>>(x, Wk, nullptr, Kb, NROWS, DIM, DIM);
        gemm_nt_kernel<<<gemm_grid, 256, 0, stream>>>(x, Wv, nullptr, Vb, NROWS, DIM, DIM);
        rmsnorm_rope_kernel<<<NROWS, 256, 0, stream>>>(Qb, gq, freqs);
        rmsnorm_rope_kernel<<<NROWS, 256, 0, stream>>>(Kb, gk, freqs);
        attn_kernel<<<dim3(SEQ / BQ, NH, BATCH), 256, 0, stream>>>(Qb, Kb, Vb, seq_lens, Ab);
        gemm_nt_kernel<<<gemm_grid, 256, 0, stream>>>(Ab, Wo, bo, out, NROWS, DIM, DIM);
    }
}

// Round 5
// 648.363 us; speedup vs baseline: 5.3040x; 1.1591x over previous
//
#include <hip/hip_runtime.h>
#include <hip/hip_bf16.h>
#include <math.h>

#define BATCH 2
#define SEQ   2048
#define DIM   2048
#define NH    16
#define HD    128
#define NROWS (BATCH * SEQ)   // 4096
#define EPS_RMS 1e-6f

typedef unsigned short ushort_t;
typedef unsigned int   uint_t;
typedef __bf16    bf16x8 __attribute__((ext_vector_type(8)));
typedef _Float16  f16x8  __attribute__((ext_vector_type(8)));
typedef float     f32x4  __attribute__((ext_vector_type(4)));

// ======================================================= fp32 -> bf16 (RNE)
__device__ inline ushort_t f2bf(float f) {
    uint_t u = __builtin_bit_cast(uint_t, f);
    uint_t r = u + 0x7FFFu + ((u >> 16) & 1u);
    return (ushort_t)(r >> 16);
}
__device__ inline ushort_t f2h(float f) {
    return __builtin_bit_cast(ushort_t, (_Float16)f);
}

// ============================== x fp32 -> fp16 (8 elems/thread)
__global__ __launch_bounds__(256) void cvt_f16_kernel(
    const float* __restrict__ src, ushort_t* __restrict__ dst, const int n)
{
    const int i = (blockIdx.x * 256 + threadIdx.x) << 3;
    if (i >= n) return;
    float v[8];
    *(float4*)&v[0] = *(const float4*)&src[i];
    *(float4*)&v[4] = *(const float4*)&src[i + 4];
    uint_t pk[4];
#pragma unroll
    for (int j = 0; j < 4; ++j)
        pk[j] = (uint_t)f2h(v[2 * j]) | ((uint_t)f2h(v[2 * j + 1]) << 16);
    *(uint4*)&dst[i] = make_uint4(pk[0], pk[1], pk[2], pk[3]);
}

// ============================== W fp32 -> fp16 hi + fp16 (lo * 2048)
__global__ __launch_bounds__(256) void split_f16_kernel(
    const float* __restrict__ src, ushort_t* __restrict__ hi,
    ushort_t* __restrict__ lo, const int n)
{
    const int i = (blockIdx.x * 256 + threadIdx.x) << 3;
    if (i >= n) return;
    float v[8];
    *(float4*)&v[0] = *(const float4*)&src[i];
    *(float4*)&v[4] = *(const float4*)&src[i + 4];
    uint_t hp[4], lp[4];
#pragma unroll
    for (int j = 0; j < 4; ++j) {
        const _Float16 h0 = (_Float16)v[2 * j];
        const _Float16 h1 = (_Float16)v[2 * j + 1];
        const _Float16 l0 = (_Float16)((v[2 * j]     - (float)h0) * 2048.0f);
        const _Float16 l1 = (_Float16)((v[2 * j + 1] - (float)h1) * 2048.0f);
        hp[j] = (uint_t)__builtin_bit_cast(ushort_t, h0) | ((uint_t)__builtin_bit_cast(ushort_t, h1) << 16);
        lp[j] = (uint_t)__builtin_bit_cast(ushort_t, l0) | ((uint_t)__builtin_bit_cast(ushort_t, l1) << 16);
    }
    *(uint4*)&hi[i] = make_uint4(hp[0], hp[1], hp[2], hp[3]);
    *(uint4*)&lo[i] = make_uint4(lp[0], lp[1], lp[2], lp[3]);
}

// ========================== fp16 2-MFMA split GEMM: C = Ah @ (Bh + Bl/2048)^T
// 128x128 tile, BK=32, 4 waves 2x2, dual accumulators.
// MODE 0: fp32 C (+bias). MODE 1: bf16 transposed Vt[b,h,d,s] output.
template<int MODE>
__global__ __launch_bounds__(256, 2) void gemm_f16x2_kernel(
    const ushort_t* __restrict__ Ah, const ushort_t* __restrict__ Bh,
    const ushort_t* __restrict__ Bl, const float* __restrict__ bias,
    float* __restrict__ C, ushort_t* __restrict__ Ct,
    const int M, const int N, const int K)
{
    __shared__ __align__(16) ushort_t sA[4096], sBh[4096], sBl[4096];
    const int tid  = threadIdx.x;
    const int w    = tid >> 6;
    const int lane = tid & 63;
    const int m0 = blockIdx.y * 128;
    const int n0 = blockIdx.x * 128;

    const int scol = (lane & 3) << 3;
    const int wr = w >> 1, wc = w & 1;
    const int fr = lane & 15, quad = lane >> 4;

    f32x4 acc1[4][4], acc2[4][4];
#pragma unroll
    for (int mi = 0; mi < 4; ++mi)
#pragma unroll
        for (int ni = 0; ni < 4; ++ni) {
            acc1[mi][ni] = (f32x4){0.f, 0.f, 0.f, 0.f};
            acc2[mi][ni] = (f32x4){0.f, 0.f, 0.f, 0.f};
        }

    for (int k0 = 0; k0 < K; k0 += 32) {
        __syncthreads();
#pragma unroll
        for (int it = 0; it < 2; ++it) {
            const int row  = (w << 5) + (it << 4) + (lane >> 2);
            const int loff = (w << 10) + (it << 9);
            const size_t ga = (size_t)(m0 + row) * K + k0 + scol;
            const size_t gb = (size_t)(n0 + row) * K + k0 + scol;
            __builtin_amdgcn_global_load_lds(
                (const __attribute__((address_space(1))) uint_t*)(const void*)(Ah + ga),
                (__attribute__((address_space(3))) uint_t*)(void*)&sA[loff], 16, 0, 0);
            __builtin_amdgcn_global_load_lds(
                (const __attribute__((address_space(1))) uint_t*)(const void*)(Bh + gb),
                (__attribute__((address_space(3))) uint_t*)(void*)&sBh[loff], 16, 0, 0);
            __builtin_amdgcn_global_load_lds(
                (const __attribute__((address_space(1))) uint_t*)(const void*)(Bl + gb),
                (__attribute__((address_space(3))) uint_t*)(void*)&sBl[loff], 16, 0, 0);
        }
        __syncthreads();

        f16x8 bh[4], bl[4];
#pragma unroll
        for (int ni = 0; ni < 4; ++ni) {
            const int row = (wc << 6) + (ni << 4) + fr;
            bh[ni] = *(const f16x8*)&sBh[(row << 5) + (quad << 3)];
            bl[ni] = *(const f16x8*)&sBl[(row << 5) + (quad << 3)];
        }
#pragma unroll
        for (int mi = 0; mi < 4; ++mi) {
            const int row = (wr << 6) + (mi << 4) + fr;
            const f16x8 ah = *(const f16x8*)&sA[(row << 5) + (quad << 3)];
#pragma unroll
            for (int ni = 0; ni < 4; ++ni) {
                acc1[mi][ni] = __builtin_amdgcn_mfma_f32_16x16x32_f16(ah, bh[ni], acc1[mi][ni], 0, 0, 0);
                acc2[mi][ni] = __builtin_amdgcn_mfma_f32_16x16x32_f16(ah, bl[ni], acc2[mi][ni], 0, 0, 0);
            }
        }
    }

    const float ls = 1.0f / 2048.0f;
#pragma unroll
    for (int mi = 0; mi < 4; ++mi)
#pragma unroll
        for (int ni = 0; ni < 4; ++ni) {
            const int col = n0 + (wc << 6) + (ni << 4) + fr;
            if (MODE == 0) {
                const float bv = bias ? bias[col] : 0.f;
#pragma unroll
                for (int r = 0; r < 4; ++r) {
                    const int rowg = m0 + (wr << 6) + (mi << 4) + (quad << 2) + r;
                    C[(size_t)rowg * N + col] =
                        acc1[mi][ni][r] + acc2[mi][ni][r] * ls + bv;
                }
            } else {
                // transposed bf16 Vt[b,h,d,s]; 4 consecutive tokens -> uint2
                const int rowg = m0 + (wr << 6) + (mi << 4) + (quad << 2);
                const int bb = rowg >> 11, tok = rowg & (SEQ - 1);
                const int hh = col >> 7, d = col & (HD - 1);
                float c[4];
#pragma unroll
                for (int r = 0; r < 4; ++r)
                    c[r] = acc1[mi][ni][r] + acc2[mi][ni][r] * ls;
                uint2 pk;
                pk.x = (uint_t)f2bf(c[0]) | ((uint_t)f2bf(c[1]) << 16);
                pk.y = (uint_t)f2bf(c[2]) | ((uint_t)f2bf(c[3]) << 16);
                *(uint2*)&Ct[((size_t)(bb * NH + hh) * HD + d) * SEQ + tok] = pk;
            }
        }
}

// ===================================================================== GEMM (fp32 fallback)
#define BM 64
#define BN 64
#define BK 16

__global__ __launch_bounds__(256) void gemm_nt_kernel(
    const float* __restrict__ A, const float* __restrict__ W,
    const float* __restrict__ bias, float* __restrict__ C,
    const int M, const int N, const int K)
{
    __shared__ float As[BK][BM + 4];
    __shared__ float Bs[BK][BN + 4];
    const int tid = threadIdx.x;
    const int tx = tid & 15;
    const int ty = tid >> 4;
    const int m0 = blockIdx.y * BM;
    const int n0 = blockIdx.x * BN;
    const int ldr = tid >> 2;
    const int ldc = (tid & 3) << 2;

    float acc[4][4] = {};

    for (int k0 = 0; k0 < K; k0 += BK) {
        __syncthreads();
        const float4 av = *(const float4*)&A[(size_t)(m0 + ldr) * K + (k0 + ldc)];
        const float4 wv = *(const float4*)&W[(size_t)(n0 + ldr) * K + (k0 + ldc)];
        As[ldc + 0][ldr] = av.x; As[ldc + 1][ldr] = av.y;
        As[ldc + 2][ldr] = av.z; As[ldc + 3][ldr] = av.w;
        Bs[ldc + 0][ldr] = wv.x; Bs[ldc + 1][ldr] = wv.y;
        Bs[ldc + 2][ldr] = wv.z; Bs[ldc + 3][ldr] = wv.w;
        __syncthreads();
#pragma unroll
        for (int k = 0; k < BK; ++k) {
            const float4 a4 = *(const float4*)&As[k][ty << 2];
            const float4 b4 = *(const float4*)&Bs[k][tx << 2];
            const float aa[4] = {a4.x, a4.y, a4.z, a4.w};
            const float bb[4] = {b4.x, b4.y, b4.z, b4.w};
#pragma unroll
            for (int i = 0; i < 4; ++i)
#pragma unroll
                for (int j = 0; j < 4; ++j)
                    acc[i][j] = fmaf(aa[i], bb[j], acc[i][j]);
        }
    }

#pragma unroll
    for (int i = 0; i < 4; ++i) {
        const int row = m0 + (ty << 2) + i;
        const int col = n0 + (tx << 2);
        float4 ov;
        ov.x = acc[i][0]; ov.y = acc[i][1]; ov.z = acc[i][2]; ov.w = acc[i][3];
        if (bias != nullptr) {
            ov.x += bias[col + 0]; ov.y += bias[col + 1];
            ov.z += bias[col + 2]; ov.w += bias[col + 3];
        }
        *(float4*)&C[(size_t)row * N + col] = ov;
    }
}

// ============================================ RMS + RoPE (fp32 in, bf16 out)
__global__ __launch_bounds__(256) void rmsnorm_rope_bf16_kernel(
    const float* __restrict__ T, const float* __restrict__ g,
    const float* __restrict__ freqs, ushort_t* __restrict__ out)
{
    const int r = blockIdx.x;
    const int s = r & (SEQ - 1);
    const int tid = threadIdx.x;
    const int base = tid << 3;

    float v[8];
    *(float4*)&v[0] = *(const float4*)&T[(size_t)r * DIM + base];
    *(float4*)&v[4] = *(const float4*)&T[(size_t)r * DIM + base + 4];

    float ss = 0.f;
#pragma unroll
    for (int i = 0; i < 8; ++i) ss += v[i] * v[i];
#pragma unroll
    for (int off = 32; off > 0; off >>= 1) ss += __shfl_down(ss, off);

    __shared__ float wsum[4];
    __shared__ float inv_sh;
    if ((tid & 63) == 0) wsum[tid >> 6] = ss;
    __syncthreads();
    if (tid == 0)
        inv_sh = rsqrtf((wsum[0] + wsum[1] + wsum[2] + wsum[3]) * (1.0f / DIM) + EPS_RMS);
    __syncthreads();
    const float inv = inv_sh;

    float gg[8];
    *(float4*)&gg[0] = *(const float4*)&g[base];
    *(float4*)&gg[4] = *(const float4*)&g[base + 4];
#pragma unroll
    for (int i = 0; i < 8; ++i) v[i] *= inv * gg[i];

    const int p0 = (base & (HD - 1)) >> 1;
#pragma unroll
    for (int pp = 0; pp < 4; ++pp) {
        float sn, cs;
        __sincosf(freqs[(size_t)s * (HD / 2) + p0 + pp], &sn, &cs);
        const float t0 = v[2 * pp], t1 = v[2 * pp + 1];
        v[2 * pp]     = t0 * cs - t1 * sn;
        v[2 * pp + 1] = t0 * sn + t1 * cs;
    }

    uint_t pk[4];
#pragma unroll
    for (int j = 0; j < 4; ++j)
        pk[j] = (uint_t)f2bf(v[2 * j]) | ((uint_t)f2bf(v[2 * j + 1]) << 16);
    *(uint4*)&out[(size_t)r * DIM + base] = make_uint4(pk[0], pk[1], pk[2], pk[3]);
}

// ================================== RMS + RoPE (fp32 in/out, fallback path)
__global__ __launch_bounds__(256) void rmsnorm_rope_kernel(
    float* __restrict__ T, const float* __restrict__ g,
    const float* __restrict__ freqs)
{
    const int r = blockIdx.x;
    const int s = r & (SEQ - 1);
    const int tid = threadIdx.x;
    const int base = tid << 3;

    float v[8];
    *(float4*)&v[0] = *(const float4*)&T[(size_t)r * DIM + base];
    *(float4*)&v[4] = *(const float4*)&T[(size_t)r * DIM + base + 4];

    float ss = 0.f;
#pragma unroll
    for (int i = 0; i < 8; ++i) ss += v[i] * v[i];
#pragma unroll
    for (int off = 32; off > 0; off >>= 1) ss += __shfl_down(ss, off);

    __shared__ float wsum[4];
    __shared__ float inv_sh;
    if ((tid & 63) == 0) wsum[tid >> 6] = ss;
    __syncthreads();
    if (tid == 0)
        inv_sh = rsqrtf((wsum[0] + wsum[1] + wsum[2] + wsum[3]) * (1.0f / DIM) + EPS_RMS);
    __syncthreads();
    const float inv = inv_sh;

    float gg[8];
    *(float4*)&gg[0] = *(const float4*)&g[base];
    *(float4*)&gg[4] = *(const float4*)&g[base + 4];
#pragma unroll
    for (int i = 0; i < 8; ++i) v[i] *= inv * gg[i];

    const int p0 = (base & (HD - 1)) >> 1;
#pragma unroll
    for (int pp = 0; pp < 4; ++pp) {
        float sn, cs;
        __sincosf(freqs[(size_t)s * (HD / 2) + p0 + pp], &sn, &cs);
        const float t0 = v[2 * pp], t1 = v[2 * pp + 1];
        v[2 * pp]     = t0 * cs - t1 * sn;
        v[2 * pp + 1] = t0 * sn + t1 * cs;
    }

    *(float4*)&T[(size_t)r * DIM + base]     = *(float4*)&v[0];
    *(float4*)&T[(size_t)r * DIM + base + 4] = *(float4*)&v[4];
}

// ======================================================== MFMA flash attention
// 128 queries/block, 4 waves x 32 queries, 64-key tiles. Epilogue: fp16 out.
#define AQ 128
#define AK 64
#define KSTR 136   // sK row stride (elems): 272 B
#define VSTR 72    // sVt/sP row stride (elems): 144 B

__global__ __launch_bounds__(256, 2) void attn_mfma_kernel(
    const ushort_t* __restrict__ QH, const ushort_t* __restrict__ KH,
    const ushort_t* __restrict__ VtG, const int* __restrict__ seq_lens,
    ushort_t* __restrict__ Oh)
{
    __shared__ __align__(16) ushort_t sK[AK * KSTR];    // [key][hd]
    __shared__ __align__(16) ushort_t sVt[HD * VSTR];   // [d][key]
    __shared__ __align__(16) ushort_t sP[AQ * VSTR];    // [query][key]

    const int tid  = threadIdx.x;
    const int w    = tid >> 6;
    const int lane = tid & 63;
    const int fr   = lane & 15;
    const int quad = lane >> 4;
    const int q0   = blockIdx.x * AQ;
    const int h    = blockIdx.y;
    const int b    = blockIdx.z;
    const int len  = seq_lens[b];
    const float scale = 0.088388347648318447f;  // 128^-0.5

    bf16x8 qfrag[2][4];
#pragma unroll
    for (int qt = 0; qt < 2; ++qt)
#pragma unroll
        for (int h4 = 0; h4 < 4; ++h4) {
            const size_t qrow = (size_t)(b * SEQ + q0 + (w << 5) + (qt << 4) + fr);
            qfrag[qt][h4] = *(const bf16x8*)&QH[qrow * DIM + h * HD + (h4 << 5) + (quad << 3)];
        }

    f32x4 Oacc[2][8];
#pragma unroll
    for (int qt = 0; qt < 2; ++qt)
#pragma unroll
        for (int dt = 0; dt < 8; ++dt)
            Oacc[qt][dt] = (f32x4){0.f, 0.f, 0.f, 0.f};
    float mrow[2] = {-1.0e30f, -1.0e30f};
    float lrow[2] = {0.f, 0.f};

    const int ntiles = (len + AK - 1) / AK;
    for (int t = 0; t < ntiles; ++t) {
        const int k0 = t * AK;
        __syncthreads();
        for (int i = tid; i < AK * 16; i += 256) {
            const int key = i >> 4, c8 = (i & 15) << 3;
            const uint4 kv = *(const uint4*)&KH[(size_t)(b * SEQ + k0 + key) * DIM + h * HD + c8];
            *(uint4*)&sK[key * KSTR + c8] = kv;
        }
        for (int i = tid; i < HD * 8; i += 256) {
            const int d = i >> 3, kc = (i & 7) << 3;
            const uint4 vv = *(const uint4*)&VtG[((size_t)(b * NH + h) * HD + d) * SEQ + k0 + kc];
            *(uint4*)&sVt[d * VSTR + kc] = vv;
        }
        __syncthreads();

        f32x4 S[4][2];
#pragma unroll
        for (int kt = 0; kt < 4; ++kt) {
            bf16x8 kf[4];
#pragma unroll
            for (int h4 = 0; h4 < 4; ++h4)
                kf[h4] = *(const bf16x8*)&sK[((kt << 4) + fr) * KSTR + (h4 << 5) + (quad << 3)];
#pragma unroll
            for (int qt = 0; qt < 2; ++qt) {
                f32x4 a = (f32x4){0.f, 0.f, 0.f, 0.f};
#pragma unroll
                for (int h4 = 0; h4 < 4; ++h4)
                    a = __builtin_amdgcn_mfma_f32_16x16x32_bf16(kf[h4], qfrag[qt][h4], a, 0, 0, 0);
                S[kt][qt] = a;
            }
        }

#pragma unroll
        for (int qt = 0; qt < 2; ++qt) {
            float tm = -1.0e30f;
#pragma unroll
            for (int kt = 0; kt < 4; ++kt)
#pragma unroll
                for (int r = 0; r < 4; ++r) {
                    const int key = k0 + (kt << 4) + (quad << 2) + r;
                    float s = S[kt][qt][r] * scale;
                    s = (key < len) ? s : -1.0e30f;
                    S[kt][qt][r] = s;
                    tm = fmaxf(tm, s);
                }
            tm = fmaxf(tm, __shfl_xor(tm, 16));
            tm = fmaxf(tm, __shfl_xor(tm, 32));
            const float mnew = fmaxf(mrow[qt], tm);
            const float alpha = __expf(mrow[qt] - mnew);
            mrow[qt] = mnew;
            float rsum = 0.f;
#pragma unroll
            for (int kt = 0; kt < 4; ++kt) {
                float p[4];
#pragma unroll
                for (int r = 0; r < 4; ++r) {
                    p[r] = __expf(S[kt][qt][r] - mnew);
                    rsum += p[r];
                }
                uint2 pk;
                pk.x = (uint_t)f2bf(p[0]) | ((uint_t)f2bf(p[1]) << 16);
                pk.y = (uint_t)f2bf(p[2]) | ((uint_t)f2bf(p[3]) << 16);
                *(uint2*)&sP[((w << 5) + (qt << 4) + fr) * VSTR + (kt << 4) + (quad << 2)] = pk;
            }
            rsum += __shfl_xor(rsum, 16);
            rsum += __shfl_xor(rsum, 32);
            lrow[qt] = lrow[qt] * alpha + rsum;
#pragma unroll
            for (int r = 0; r < 4; ++r) {
                const float ar = __shfl(alpha, (quad << 2) + r);
#pragma unroll
                for (int dt = 0; dt < 8; ++dt)
                    Oacc[qt][dt][r] *= ar;
            }
        }

#pragma unroll
        for (int ks = 0; ks < 2; ++ks) {
            bf16x8 pf[2];
#pragma unroll
            for (int qt = 0; qt < 2; ++qt)
                pf[qt] = *(const bf16x8*)&sP[((w << 5) + (qt << 4) + fr) * VSTR + (ks << 5) + (quad << 3)];
#pragma unroll
            for (int dt = 0; dt < 8; ++dt) {
                const bf16x8 vf = *(const bf16x8*)&sVt[((dt << 4) + fr) * VSTR + (ks << 5) + (quad << 3)];
#pragma unroll
                for (int qt = 0; qt < 2; ++qt)
                    Oacc[qt][dt] = __builtin_amdgcn_mfma_f32_16x16x32_bf16(pf[qt], vf, Oacc[qt][dt], 0, 0, 0);
            }
        }
    }

    // ---- writeout (fp16, feeds final GEMM A-side directly)
#pragma unroll
    for (int qt = 0; qt < 2; ++qt) {
        float linv[4];
#pragma unroll
        for (int r = 0; r < 4; ++r)
            linv[r] = 1.0f / __shfl(lrow[qt], (quad << 2) + r);
#pragma unroll
        for (int dt = 0; dt < 8; ++dt)
#pragma unroll
            for (int r = 0; r < 4; ++r) {
                const int qrow = q0 + (w << 5) + (qt << 4) + (quad << 2) + r;
                Oh[(size_t)(b * SEQ + qrow) * DIM + h * HD + (dt << 4) + fr] =
                    f2h(Oacc[qt][dt][r] * linv[r]);
            }
    }
}

// ======================================== fp32 flash attention (fallback)
#define BQ  64
#define BKT 64

__global__ __launch_bounds__(256) void attn_kernel(
    const float* __restrict__ Q, const float* __restrict__ K,
    const float* __restrict__ V, const int* __restrict__ seq_lens,
    float* __restrict__ O)
{
    const int qt = blockIdx.x;
    const int h  = blockIdx.y;
    const int b  = blockIdx.z;
    const int len = seq_lens[b];
    const int q0 = qt * BQ;
    const float scale = 0.088388347648318447f;

    __shared__ float Qst[HD][BQ + 4];
    __shared__ float Kst[HD][BKT + 4];
    __shared__ float Vs[BKT][HD + 4];
    __shared__ float Sc[BQ][BKT + 1];
    __shared__ float mrow[BQ], lrow[BQ], alpha_s[BQ];

    const int tid = threadIdx.x;
    const int si0 = (tid >> 4) << 2;
    const int sj0 = (tid & 15) << 2;
    const int pi0 = (tid >> 4) << 2;
    const int pc0 = (tid & 15) << 3;

    for (int i = tid; i < BQ * HD / 4; i += 256) {
        const int e = i << 2;
        const int row = e >> 7;
        const int c0 = e & (HD - 1);
        const float4 qv = *(const float4*)&Q[(size_t)(b * SEQ + q0 + row) * DIM + h * HD + c0];
        Qst[c0 + 0][row] = qv.x; Qst[c0 + 1][row] = qv.y;
        Qst[c0 + 2][row] = qv.z; Qst[c0 + 3][row] = qv.w;
    }
    if (tid < BQ) { mrow[tid] = -3.0e38f; lrow[tid] = 0.f; }

    float o[4][8] = {};
    __syncthreads();

    const int ntiles = (len + BKT - 1) / BKT;
    for (int t = 0; t < ntiles; ++t) {
        const int k0 = t * BKT;
        __syncthreads();
        for (int i = tid; i < BKT * HD / 4; i += 256) {
            const int e = i << 2;
            const int row = e >> 7;
            const int c0 = e & (HD - 1);
            const int kg = k0 + row;
            float4 kv = make_float4(0.f, 0.f, 0.f, 0.f);
            float4 vv = make_float4(0.f, 0.f, 0.f, 0.f);
            if (kg < len) {
                kv = *(const float4*)&K[(size_t)(b * SEQ + kg) * DIM + h * HD + c0];
                vv = *(const float4*)&V[(size_t)(b * SEQ + kg) * DIM + h * HD + c0];
            }
            Kst[c0 + 0][row] = kv.x; Kst[c0 + 1][row] = kv.y;
            Kst[c0 + 2][row] = kv.z; Kst[c0 + 3][row] = kv.w;
            *(float4*)&Vs[row][c0] = vv;
        }
        __syncthreads();

        float acc[4][4] = {};
#pragma unroll 8
        for (int kk = 0; kk < HD; ++kk) {
            const float4 q4 = *(const float4*)&Qst[kk][si0];
            const float4 k4 = *(const float4*)&Kst[kk][sj0];
            const float qa[4] = {q4.x, q4.y, q4.z, q4.w};
            const float ka[4] = {k4.x, k4.y, k4.z, k4.w};
#pragma unroll
            for (int i = 0; i < 4; ++i)
#pragma unroll
                for (int j = 0; j < 4; ++j)
                    acc[i][j] = fmaf(qa[i], ka[j], acc[i][j]);
        }
#pragma unroll
        for (int i = 0; i < 4; ++i)
#pragma unroll
            for (int j = 0; j < 4; ++j) {
                const int jg = k0 + sj0 + j;
                Sc[si0 + i][sj0 + j] = (jg < len) ? acc[i][j] * scale : -1.0e9f;
            }
        __syncthreads();

        if (tid < BQ) {
            const int i = tid;
            const float m_old = mrow[i];
            float mx = m_old;
            for (int j = 0; j < BKT; ++j) mx = fmaxf(mx, Sc[i][j]);
            const float al = __expf(m_old - mx);
            float sum = 0.f;
            for (int j = 0; j < BKT; ++j) {
                const float p = __expf(Sc[i][j] - mx);
                Sc[i][j] = p;
                sum += p;
            }
            mrow[i] = mx;
            lrow[i] = lrow[i] * al + sum;
            alpha_s[i] = al;
        }
        __syncthreads();

#pragma unroll
        for (int i = 0; i < 4; ++i) {
            const float al = alpha_s[pi0 + i];
#pragma unroll
            for (int c = 0; c < 8; ++c) o[i][c] *= al;
        }
        for (int j = 0; j < BKT; ++j) {
            float p[4];
#pragma unroll
            for (int i = 0; i < 4; ++i) p[i] = Sc[pi0 + i][j];
            const float4 v0 = *(const float4*)&Vs[j][pc0];
            const float4 v1 = *(const float4*)&Vs[j][pc0 + 4];
            const float va[8] = {v0.x, v0.y, v0.z, v0.w, v1.x, v1.y, v1.z, v1.w};
#pragma unroll
            for (int i = 0; i < 4; ++i)
#pragma unroll
                for (int c = 0; c < 8; ++c)
                    o[i][c] = fmaf(p[i], va[c], o[i][c]);
        }
    }

#pragma unroll
    for (int i = 0; i < 4; ++i) {
        const float invl = 1.0f / lrow[pi0 + i];
        float4 w0, w1;
        w0.x = o[i][0] * invl; w0.y = o[i][1] * invl;
        w0.z = o[i][2] * invl; w0.w = o[i][3] * invl;
        w1.x = o[i][4] * invl; w1.y = o[i][5] * invl;
        w1.z = o[i][6] * invl; w1.w = o[i][7] * invl;
        float* op = &O[(size_t)(b * SEQ + q0 + pi0 + i) * DIM + h * HD + pc0];
        *(float4*)&op[0] = w0;
        *(float4*)&op[4] = w1;
    }
}

// ==================================================================== launch
extern "C" void kernel_launch(void* const* d_in, const int* in_sizes, int n_in,
                              void* d_out, int out_size, void* d_ws, size_t ws_size,
                              hipStream_t stream)
{
    const float* x        = (const float*)d_in[0];
    const int*   seq_lens = (const int*)d_in[1];
    const float* freqs    = (const float*)d_in[3];
    const float* Wq       = (const float*)d_in[4];
    const float* Wk       = (const float*)d_in[5];
    const float* Wv       = (const float*)d_in[6];
    const float* Wo       = (const float*)d_in[7];
    const float* bo       = (const float*)d_in[8];
    const float* gq       = (const float*)d_in[9];
    const float* gk       = (const float*)d_in[10];
    float* out = (float*)d_out;

    const size_t mat = (size_t)NROWS * DIM;       // 8.39M elems
    const size_t wsz = (size_t)DIM * DIM;         // 4.19M elems

    // ---- MFMA-path workspace layout (218 MB total) ----
    float*    Qb   = (float*)d_ws;                 // mat fp32
    float*    Kb   = Qb + mat;                     // mat fp32
    ushort_t* xh   = (ushort_t*)(Kb + mat);        // mat fp16
    ushort_t* wqh  = xh + mat;                     // wsz fp16 x8 (hi/lo x4 W)
    ushort_t* wql  = wqh + wsz;
    ushort_t* wkh  = wql + wsz;
    ushort_t* wkl  = wkh + wsz;
    ushort_t* wvh  = wkl + wsz;
    ushort_t* wvl  = wvh + wsz;
    ushort_t* woh  = wvl + wsz;
    ushort_t* wol  = woh + wsz;
    ushort_t* qbh  = wol + wsz;                    // mat bf16
    ushort_t* kbh  = qbh + mat;                    // mat bf16
    ushort_t* vtg  = kbh + mat;                    // mat bf16 (transposed V)
    ushort_t* abh  = vtg + mat;                    // mat fp16 (attn out)

    const size_t need = 2 * mat * sizeof(float)
                      + (mat + 8 * wsz + 3 * mat + mat) * sizeof(ushort_t);

    if (ws_size >= need) {
        // ================= fp16-split MFMA path =================
        cvt_f16_kernel  <<<(int)(mat / (256 * 8)), 256, 0, stream>>>(x, xh, (int)mat);
        split_f16_kernel<<<(int)(wsz / (256 * 8)), 256, 0, stream>>>(Wq, wqh, wql, (int)wsz);
        split_f16_kernel<<<(int)(wsz / (256 * 8)), 256, 0, stream>>>(Wk, wkh, wkl, (int)wsz);
        split_f16_kernel<<<(int)(wsz / (256 * 8)), 256, 0, stream>>>(Wv, wvh, wvl, (int)wsz);
        split_f16_kernel<<<(int)(wsz / (256 * 8)), 256, 0, stream>>>(Wo, woh, wol, (int)wsz);

        const dim3 gg(DIM / 128, NROWS / 128);
        gemm_f16x2_kernel<0><<<gg, 256, 0, stream>>>(xh, wqh, wql, nullptr, Qb, nullptr, NROWS, DIM, DIM);
        gemm_f16x2_kernel<0><<<gg, 256, 0, stream>>>(xh, wkh, wkl, nullptr, Kb, nullptr, NROWS, DIM, DIM);
        gemm_f16x2_kernel<1><<<gg, 256, 0, stream>>>(xh, wvh, wvl, nullptr, nullptr, vtg, NROWS, DIM, DIM);

        rmsnorm_rope_bf16_kernel<<<NROWS, 256, 0, stream>>>(Qb, gq, freqs, qbh);
        rmsnorm_rope_bf16_kernel<<<NROWS, 256, 0, stream>>>(Kb, gk, freqs, kbh);

        attn_mfma_kernel<<<dim3(SEQ / AQ, NH, BATCH), 256, 0, stream>>>(qbh, kbh, vtg, seq_lens, abh);

        gemm_f16x2_kernel<0><<<gg, 256, 0, stream>>>(abh, woh, wol, bo, out, nullptr, NROWS, DIM, DIM);
    } else {
        // ================= fp32 fallback (134 MB) =================
        float* Vb = Kb + mat;   // reuse region: Qb,Kb,Vb,Ab fp32
        float* Ab = Vb + mat;
        const dim3 gemm_grid(DIM / BN, NROWS / BM);
        gemm_nt_kernel<<<gemm_grid, 256, 0, stream>>>(x, Wq, nullptr, Qb, NROWS, DIM, DIM);
        gemm_nt_kernel<<<gemm_grid, 256, 0, stream>>>(x, Wk, nullptr, Kb, NROWS, DIM, DIM);
        gemm_nt_kernel<<<gemm_grid, 256, 0, stream>>>(x, Wv, nullptr, Vb, NROWS, DIM, DIM);
        rmsnorm_rope_kernel<<<NROWS, 256, 0, stream>>>(Qb, gq, freqs);
        rmsnorm_rope_kernel<<<NROWS, 256, 0, stream>>>(Kb, gk, freqs);
        attn_kernel<<<dim3(SEQ / BQ, NH, BATCH), 256, 0, stream>>>(Qb, Kb, Vb, seq_lens, Ab);
        gemm_nt_kernel<<<gemm_grid, 256, 0, stream>>>(Ab, Wo, bo, out, NROWS, DIM, DIM);
    }
}

// Round 6
// 520.733 us; speedup vs baseline: 6.6039x; 1.2451x over previous
//
#include <hip/hip_runtime.h>
#include <hip/hip_bf16.h>
#include <math.h>

#define BATCH 2
#define SEQ   2048
#define DIM   2048
#define NH    16
#define HD    128
#define NROWS (BATCH * SEQ)   // 4096
#define EPS_RMS 1e-6f

typedef unsigned short ushort_t;
typedef unsigned int   uint_t;
typedef __bf16    bf16x8 __attribute__((ext_vector_type(8)));
typedef _Float16  f16x8  __attribute__((ext_vector_type(8)));
typedef float     f32x4  __attribute__((ext_vector_type(4)));

__device__ inline ushort_t f2bf(float f) {
    uint_t u = __builtin_bit_cast(uint_t, f);
    uint_t r = u + 0x7FFFu + ((u >> 16) & 1u);
    return (ushort_t)(r >> 16);
}
__device__ inline ushort_t f2h(float f) {
    return __builtin_bit_cast(ushort_t, (_Float16)f);
}

// ================= fused fp32 -> fp16 conversion: x + 4 weight matrices
// 2048 elems/block. blocks: [0,4096) x | then 4 x 2048-block weight regions.
__global__ __launch_bounds__(256) void cvt_all_kernel(
    const float* __restrict__ x,  const float* __restrict__ wq,
    const float* __restrict__ wk, const float* __restrict__ wv,
    const float* __restrict__ wo,
    ushort_t* __restrict__ xh,  ushort_t* __restrict__ wqh,
    ushort_t* __restrict__ wkh, ushort_t* __restrict__ wvh,
    ushort_t* __restrict__ woh)
{
    const int blk = blockIdx.x;
    const float* src; ushort_t* dst; size_t base;
    if (blk < 4096) { src = x; dst = xh; base = (size_t)blk * 2048; }
    else {
        const int r = blk - 4096;
        const int wsel = r >> 11;
        base = (size_t)(r & 2047) * 2048;
        if      (wsel == 0) { src = wq; dst = wqh; }
        else if (wsel == 1) { src = wk; dst = wkh; }
        else if (wsel == 2) { src = wv; dst = wvh; }
        else                { src = wo; dst = woh; }
    }
    const size_t i = base + ((size_t)threadIdx.x << 3);
    float v[8];
    *(float4*)&v[0] = *(const float4*)&src[i];
    *(float4*)&v[4] = *(const float4*)&src[i + 4];
    uint_t pk[4];
#pragma unroll
    for (int j = 0; j < 4; ++j)
        pk[j] = (uint_t)f2h(v[2 * j]) | ((uint_t)f2h(v[2 * j + 1]) << 16);
    *(uint4*)&dst[i] = make_uint4(pk[0], pk[1], pk[2], pk[3]);
}

// ========================== plain fp16 MFMA GEMM: C = A @ B^T (+bias)
// 128x128 tile, BK=32, 4 waves 2x2, 4x4 16x16x32 MFMAs/wave (m97 structure).
// MODE 0: fp32 C (+bias). MODE 1: bf16 transposed Vt[b,h,d,s] output.
template<int MODE>
__global__ __launch_bounds__(256, 2) void gemm_f16_kernel(
    const ushort_t* __restrict__ Ah, const ushort_t* __restrict__ Bh,
    const float* __restrict__ bias,
    float* __restrict__ C, ushort_t* __restrict__ Ct,
    const int M, const int N, const int K)
{
    __shared__ __align__(16) ushort_t sA[4096], sB[4096];
    const int tid  = threadIdx.x;
    const int w    = tid >> 6;
    const int lane = tid & 63;
    const int m0 = blockIdx.y * 128;
    const int n0 = blockIdx.x * 128;

    const int scol = (lane & 3) << 3;
    const int wr = w >> 1, wc = w & 1;
    const int fr = lane & 15, quad = lane >> 4;

    f32x4 acc[4][4];
#pragma unroll
    for (int mi = 0; mi < 4; ++mi)
#pragma unroll
        for (int ni = 0; ni < 4; ++ni)
            acc[mi][ni] = (f32x4){0.f, 0.f, 0.f, 0.f};

    for (int k0 = 0; k0 < K; k0 += 32) {
        __syncthreads();
#pragma unroll
        for (int it = 0; it < 2; ++it) {
            const int row  = (w << 5) + (it << 4) + (lane >> 2);
            const int loff = (w << 10) + (it << 9);
            const size_t ga = (size_t)(m0 + row) * K + k0 + scol;
            const size_t gb = (size_t)(n0 + row) * K + k0 + scol;
            __builtin_amdgcn_global_load_lds(
                (const __attribute__((address_space(1))) uint_t*)(const void*)(Ah + ga),
                (__attribute__((address_space(3))) uint_t*)(void*)&sA[loff], 16, 0, 0);
            __builtin_amdgcn_global_load_lds(
                (const __attribute__((address_space(1))) uint_t*)(const void*)(Bh + gb),
                (__attribute__((address_space(3))) uint_t*)(void*)&sB[loff], 16, 0, 0);
        }
        __syncthreads();

        f16x8 bfr[4];
#pragma unroll
        for (int ni = 0; ni < 4; ++ni) {
            const int row = (wc << 6) + (ni << 4) + fr;
            bfr[ni] = *(const f16x8*)&sB[(row << 5) + (quad << 3)];
        }
#pragma unroll
        for (int mi = 0; mi < 4; ++mi) {
            const int row = (wr << 6) + (mi << 4) + fr;
            const f16x8 ah = *(const f16x8*)&sA[(row << 5) + (quad << 3)];
#pragma unroll
            for (int ni = 0; ni < 4; ++ni)
                acc[mi][ni] = __builtin_amdgcn_mfma_f32_16x16x32_f16(ah, bfr[ni], acc[mi][ni], 0, 0, 0);
        }
    }

#pragma unroll
    for (int mi = 0; mi < 4; ++mi)
#pragma unroll
        for (int ni = 0; ni < 4; ++ni) {
            const int col = n0 + (wc << 6) + (ni << 4) + fr;
            if (MODE == 0) {
                const float bv = bias ? bias[col] : 0.f;
#pragma unroll
                for (int r = 0; r < 4; ++r) {
                    const int rowg = m0 + (wr << 6) + (mi << 4) + (quad << 2) + r;
                    C[(size_t)rowg * N + col] = acc[mi][ni][r] + bv;
                }
            } else {
                // transposed bf16 Vt[b,h,d,s]; 4 consecutive tokens -> uint2
                const int rowg = m0 + (wr << 6) + (mi << 4) + (quad << 2);
                const int bb = rowg >> 11, tok = rowg & (SEQ - 1);
                const int hh = col >> 7, d = col & (HD - 1);
                uint2 pk;
                pk.x = (uint_t)f2bf(acc[mi][ni][0]) | ((uint_t)f2bf(acc[mi][ni][1]) << 16);
                pk.y = (uint_t)f2bf(acc[mi][ni][2]) | ((uint_t)f2bf(acc[mi][ni][3]) << 16);
                *(uint2*)&Ct[((size_t)(bb * NH + hh) * HD + d) * SEQ + tok] = pk;
            }
        }
}

// ===================================================================== GEMM (fp32 fallback)
#define BM 64
#define BN 64
#define BK 16

__global__ __launch_bounds__(256) void gemm_nt_kernel(
    const float* __restrict__ A, const float* __restrict__ W,
    const float* __restrict__ bias, float* __restrict__ C,
    const int M, const int N, const int K)
{
    __shared__ float As[BK][BM + 4];
    __shared__ float Bs[BK][BN + 4];
    const int tid = threadIdx.x;
    const int tx = tid & 15;
    const int ty = tid >> 4;
    const int m0 = blockIdx.y * BM;
    const int n0 = blockIdx.x * BN;
    const int ldr = tid >> 2;
    const int ldc = (tid & 3) << 2;

    float acc[4][4] = {};

    for (int k0 = 0; k0 < K; k0 += BK) {
        __syncthreads();
        const float4 av = *(const float4*)&A[(size_t)(m0 + ldr) * K + (k0 + ldc)];
        const float4 wv = *(const float4*)&W[(size_t)(n0 + ldr) * K + (k0 + ldc)];
        As[ldc + 0][ldr] = av.x; As[ldc + 1][ldr] = av.y;
        As[ldc + 2][ldr] = av.z; As[ldc + 3][ldr] = av.w;
        Bs[ldc + 0][ldr] = wv.x; Bs[ldc + 1][ldr] = wv.y;
        Bs[ldc + 2][ldr] = wv.z; Bs[ldc + 3][ldr] = wv.w;
        __syncthreads();
#pragma unroll
        for (int k = 0; k < BK; ++k) {
            const float4 a4 = *(const float4*)&As[k][ty << 2];
            const float4 b4 = *(const float4*)&Bs[k][tx << 2];
            const float aa[4] = {a4.x, a4.y, a4.z, a4.w};
            const float bb[4] = {b4.x, b4.y, b4.z, b4.w};
#pragma unroll
            for (int i = 0; i < 4; ++i)
#pragma unroll
                for (int j = 0; j < 4; ++j)
                    acc[i][j] = fmaf(aa[i], bb[j], acc[i][j]);
        }
    }

#pragma unroll
    for (int i = 0; i < 4; ++i) {
        const int row = m0 + (ty << 2) + i;
        const int col = n0 + (tx << 2);
        float4 ov;
        ov.x = acc[i][0]; ov.y = acc[i][1]; ov.z = acc[i][2]; ov.w = acc[i][3];
        if (bias != nullptr) {
            ov.x += bias[col + 0]; ov.y += bias[col + 1];
            ov.z += bias[col + 2]; ov.w += bias[col + 3];
        }
        *(float4*)&C[(size_t)row * N + col] = ov;
    }
}

// ==================== fused RMS+RoPE for Q and K (fp32 in, bf16 out)
// grid (NROWS, 2): y==0 -> Q (pre-scaled by 1/sqrt(HD)), y==1 -> K.
__global__ __launch_bounds__(256) void rmsnorm_rope_qk_kernel(
    const float* __restrict__ Qb, const float* __restrict__ gq,
    ushort_t* __restrict__ qbh,
    const float* __restrict__ Kb, const float* __restrict__ gk,
    ushort_t* __restrict__ kbh,
    const float* __restrict__ freqs)
{
    const int r = blockIdx.x;
    const int s = r & (SEQ - 1);
    const int tid = threadIdx.x;
    const int base = tid << 3;
    const bool isQ = (blockIdx.y == 0);
    const float* T = isQ ? Qb : Kb;
    const float* g = isQ ? gq : gk;
    ushort_t* out  = isQ ? qbh : kbh;
    const float posc = isQ ? 0.088388347648318447f : 1.0f;  // fold softmax scale into Q

    float v[8];
    *(float4*)&v[0] = *(const float4*)&T[(size_t)r * DIM + base];
    *(float4*)&v[4] = *(const float4*)&T[(size_t)r * DIM + base + 4];

    float ss = 0.f;
#pragma unroll
    for (int i = 0; i < 8; ++i) ss += v[i] * v[i];
#pragma unroll
    for (int off = 32; off > 0; off >>= 1) ss += __shfl_down(ss, off);

    __shared__ float wsum[4];
    __shared__ float inv_sh;
    if ((tid & 63) == 0) wsum[tid >> 6] = ss;
    __syncthreads();
    if (tid == 0)
        inv_sh = rsqrtf((wsum[0] + wsum[1] + wsum[2] + wsum[3]) * (1.0f / DIM) + EPS_RMS);
    __syncthreads();
    const float inv = inv_sh * posc;

    float gg[8];
    *(float4*)&gg[0] = *(const float4*)&g[base];
    *(float4*)&gg[4] = *(const float4*)&g[base + 4];
#pragma unroll
    for (int i = 0; i < 8; ++i) v[i] *= inv * gg[i];

    const int p0 = (base & (HD - 1)) >> 1;
#pragma unroll
    for (int pp = 0; pp < 4; ++pp) {
        float sn, cs;
        __sincosf(freqs[(size_t)s * (HD / 2) + p0 + pp], &sn, &cs);
        const float t0 = v[2 * pp], t1 = v[2 * pp + 1];
        v[2 * pp]     = t0 * cs - t1 * sn;
        v[2 * pp + 1] = t0 * sn + t1 * cs;
    }

    uint_t pk[4];
#pragma unroll
    for (int j = 0; j < 4; ++j)
        pk[j] = (uint_t)f2bf(v[2 * j]) | ((uint_t)f2bf(v[2 * j + 1]) << 16);
    *(uint4*)&out[(size_t)r * DIM + base] = make_uint4(pk[0], pk[1], pk[2], pk[3]);
}

// ================================== RMS + RoPE (fp32 in/out, fallback path)
__global__ __launch_bounds__(256) void rmsnorm_rope_kernel(
    float* __restrict__ T, const float* __restrict__ g,
    const float* __restrict__ freqs)
{
    const int r = blockIdx.x;
    const int s = r & (SEQ - 1);
    const int tid = threadIdx.x;
    const int base = tid << 3;

    float v[8];
    *(float4*)&v[0] = *(const float4*)&T[(size_t)r * DIM + base];
    *(float4*)&v[4] = *(const float4*)&T[(size_t)r * DIM + base + 4];

    float ss = 0.f;
#pragma unroll
    for (int i = 0; i < 8; ++i) ss += v[i] * v[i];
#pragma unroll
    for (int off = 32; off > 0; off >>= 1) ss += __shfl_down(ss, off);

    __shared__ float wsum[4];
    __shared__ float inv_sh;
    if ((tid & 63) == 0) wsum[tid >> 6] = ss;
    __syncthreads();
    if (tid == 0)
        inv_sh = rsqrtf((wsum[0] + wsum[1] + wsum[2] + wsum[3]) * (1.0f / DIM) + EPS_RMS);
    __syncthreads();
    const float inv = inv_sh;

    float gg[8];
    *(float4*)&gg[0] = *(const float4*)&g[base];
    *(float4*)&gg[4] = *(const float4*)&g[base + 4];
#pragma unroll
    for (int i = 0; i < 8; ++i) v[i] *= inv * gg[i];

    const int p0 = (base & (HD - 1)) >> 1;
#pragma unroll
    for (int pp = 0; pp < 4; ++pp) {
        float sn, cs;
        __sincosf(freqs[(size_t)s * (HD / 2) + p0 + pp], &sn, &cs);
        const float t0 = v[2 * pp], t1 = v[2 * pp + 1];
        v[2 * pp]     = t0 * cs - t1 * sn;
        v[2 * pp + 1] = t0 * sn + t1 * cs;
    }

    *(float4*)&T[(size_t)r * DIM + base]     = *(float4*)&v[0];
    *(float4*)&T[(size_t)r * DIM + base + 4] = *(float4*)&v[4];
}

// ======================================================== MFMA flash attention
// 128 queries/block, 4 waves x 32 queries, 64-key tiles. Q pre-scaled.
// Masking only in the (wave-uniform) tail tile.
#define AQ 128
#define AK 64
#define KSTR 136   // sK row stride (elems): 272 B
#define VSTR 72    // sVt/sP row stride (elems): 144 B

__global__ __launch_bounds__(256, 2) void attn_mfma_kernel(
    const ushort_t* __restrict__ QH, const ushort_t* __restrict__ KH,
    const ushort_t* __restrict__ VtG, const int* __restrict__ seq_lens,
    ushort_t* __restrict__ Oh)
{
    __shared__ __align__(16) ushort_t sK[AK * KSTR];    // [key][hd]
    __shared__ __align__(16) ushort_t sVt[HD * VSTR];   // [d][key]
    __shared__ __align__(16) ushort_t sP[AQ * VSTR];    // [query][key]

    const int tid  = threadIdx.x;
    const int w    = tid >> 6;
    const int lane = tid & 63;
    const int fr   = lane & 15;
    const int quad = lane >> 4;
    const int q0   = blockIdx.x * AQ;
    const int h    = blockIdx.y;
    const int b    = blockIdx.z;
    const int len  = seq_lens[b];

    bf16x8 qfrag[2][4];
#pragma unroll
    for (int qt = 0; qt < 2; ++qt)
#pragma unroll
        for (int h4 = 0; h4 < 4; ++h4) {
            const size_t qrow = (size_t)(b * SEQ + q0 + (w << 5) + (qt << 4) + fr);
            qfrag[qt][h4] = *(const bf16x8*)&QH[qrow * DIM + h * HD + (h4 << 5) + (quad << 3)];
        }

    f32x4 Oacc[2][8];
#pragma unroll
    for (int qt = 0; qt < 2; ++qt)
#pragma unroll
        for (int dt = 0; dt < 8; ++dt)
            Oacc[qt][dt] = (f32x4){0.f, 0.f, 0.f, 0.f};
    float mrow[2] = {-1.0e30f, -1.0e30f};
    float lrow[2] = {0.f, 0.f};

    const int ntiles = (len + AK - 1) / AK;
    for (int t = 0; t < ntiles; ++t) {
        const int k0 = t * AK;
        const bool masked = (k0 + AK > len);   // wave-uniform
        __syncthreads();
        for (int i = tid; i < AK * 16; i += 256) {
            const int key = i >> 4, c8 = (i & 15) << 3;
            const uint4 kv = *(const uint4*)&KH[(size_t)(b * SEQ + k0 + key) * DIM + h * HD + c8];
            *(uint4*)&sK[key * KSTR + c8] = kv;
        }
        for (int i = tid; i < HD * 8; i += 256) {
            const int d = i >> 3, kc = (i & 7) << 3;
            const uint4 vv = *(const uint4*)&VtG[((size_t)(b * NH + h) * HD + d) * SEQ + k0 + kc];
            *(uint4*)&sVt[d * VSTR + kc] = vv;
        }
        __syncthreads();

        f32x4 S[4][2];
#pragma unroll
        for (int kt = 0; kt < 4; ++kt) {
            bf16x8 kf[4];
#pragma unroll
            for (int h4 = 0; h4 < 4; ++h4)
                kf[h4] = *(const bf16x8*)&sK[((kt << 4) + fr) * KSTR + (h4 << 5) + (quad << 3)];
#pragma unroll
            for (int qt = 0; qt < 2; ++qt) {
                f32x4 a = (f32x4){0.f, 0.f, 0.f, 0.f};
#pragma unroll
                for (int h4 = 0; h4 < 4; ++h4)
                    a = __builtin_amdgcn_mfma_f32_16x16x32_bf16(kf[h4], qfrag[qt][h4], a, 0, 0, 0);
                S[kt][qt] = a;
            }
        }

#pragma unroll
        for (int qt = 0; qt < 2; ++qt) {
            float tm = -1.0e30f;
            if (masked) {
#pragma unroll
                for (int kt = 0; kt < 4; ++kt)
#pragma unroll
                    for (int r = 0; r < 4; ++r) {
                        const int key = k0 + (kt << 4) + (quad << 2) + r;
                        float s = (key < len) ? S[kt][qt][r] : -1.0e30f;
                        S[kt][qt][r] = s;
                        tm = fmaxf(tm, s);
                    }
            } else {
#pragma unroll
                for (int kt = 0; kt < 4; ++kt)
#pragma unroll
                    for (int r = 0; r < 4; ++r)
                        tm = fmaxf(tm, S[kt][qt][r]);
            }
            tm = fmaxf(tm, __shfl_xor(tm, 16));
            tm = fmaxf(tm, __shfl_xor(tm, 32));
            const float mnew = fmaxf(mrow[qt], tm);
            const float alpha = __expf(mrow[qt] - mnew);
            mrow[qt] = mnew;
            float rsum = 0.f;
#pragma unroll
            for (int kt = 0; kt < 4; ++kt) {
                float p[4];
#pragma unroll
                for (int r = 0; r < 4; ++r) {
                    p[r] = __expf(S[kt][qt][r] - mnew);
                    rsum += p[r];
                }
                uint2 pk;
                pk.x = (uint_t)f2bf(p[0]) | ((uint_t)f2bf(p[1]) << 16);
                pk.y = (uint_t)f2bf(p[2]) | ((uint_t)f2bf(p[3]) << 16);
                *(uint2*)&sP[((w << 5) + (qt << 4) + fr) * VSTR + (kt << 4) + (quad << 2)] = pk;
            }
            rsum += __shfl_xor(rsum, 16);
            rsum += __shfl_xor(rsum, 32);
            lrow[qt] = lrow[qt] * alpha + rsum;
#pragma unroll
            for (int r = 0; r < 4; ++r) {
                const float ar = __shfl(alpha, (quad << 2) + r);
#pragma unroll
                for (int dt = 0; dt < 8; ++dt)
                    Oacc[qt][dt][r] *= ar;
            }
        }

#pragma unroll
        for (int ks = 0; ks < 2; ++ks) {
            bf16x8 pf[2];
#pragma unroll
            for (int qt = 0; qt < 2; ++qt)
                pf[qt] = *(const bf16x8*)&sP[((w << 5) + (qt << 4) + fr) * VSTR + (ks << 5) + (quad << 3)];
#pragma unroll
            for (int dt = 0; dt < 8; ++dt) {
                const bf16x8 vf = *(const bf16x8*)&sVt[((dt << 4) + fr) * VSTR + (ks << 5) + (quad << 3)];
#pragma unroll
                for (int qt = 0; qt < 2; ++qt)
                    Oacc[qt][dt] = __builtin_amdgcn_mfma_f32_16x16x32_bf16(pf[qt], vf, Oacc[qt][dt], 0, 0, 0);
            }
        }
    }

    // ---- writeout (fp16, feeds final GEMM A-side directly)
#pragma unroll
    for (int qt = 0; qt < 2; ++qt) {
        float linv[4];
#pragma unroll
        for (int r = 0; r < 4; ++r)
            linv[r] = 1.0f / __shfl(lrow[qt], (quad << 2) + r);
#pragma unroll
        for (int dt = 0; dt < 8; ++dt)
#pragma unroll
            for (int r = 0; r < 4; ++r) {
                const int qrow = q0 + (w << 5) + (qt << 4) + (quad << 2) + r;
                Oh[(size_t)(b * SEQ + qrow) * DIM + h * HD + (dt << 4) + fr] =
                    f2h(Oacc[qt][dt][r] * linv[r]);
            }
    }
}

// ======================================== fp32 flash attention (fallback)
#define BQ  64
#define BKT 64

__global__ __launch_bounds__(256) void attn_kernel(
    const float* __restrict__ Q, const float* __restrict__ K,
    const float* __restrict__ V, const int* __restrict__ seq_lens,
    float* __restrict__ O)
{
    const int qt = blockIdx.x;
    const int h  = blockIdx.y;
    const int b  = blockIdx.z;
    const int len = seq_lens[b];
    const int q0 = qt * BQ;
    const float scale = 0.088388347648318447f;

    __shared__ float Qst[HD][BQ + 4];
    __shared__ float Kst[HD][BKT + 4];
    __shared__ float Vs[BKT][HD + 4];
    __shared__ float Sc[BQ][BKT + 1];
    __shared__ float mrow[BQ], lrow[BQ], alpha_s[BQ];

    const int tid = threadIdx.x;
    const int si0 = (tid >> 4) << 2;
    const int sj0 = (tid & 15) << 2;
    const int pi0 = (tid >> 4) << 2;
    const int pc0 = (tid & 15) << 3;

    for (int i = tid; i < BQ * HD / 4; i += 256) {
        const int e = i << 2;
        const int row = e >> 7;
        const int c0 = e & (HD - 1);
        const float4 qv = *(const float4*)&Q[(size_t)(b * SEQ + q0 + row) * DIM + h * HD + c0];
        Qst[c0 + 0][row] = qv.x; Qst[c0 + 1][row] = qv.y;
        Qst[c0 + 2][row] = qv.z; Qst[c0 + 3][row] = qv.w;
    }
    if (tid < BQ) { mrow[tid] = -3.0e38f; lrow[tid] = 0.f; }

    float o[4][8] = {};
    __syncthreads();

    const int ntiles = (len + BKT - 1) / BKT;
    for (int t = 0; t < ntiles; ++t) {
        const int k0 = t * BKT;
        __syncthreads();
        for (int i = tid; i < BKT * HD / 4; i += 256) {
            const int e = i << 2;
            const int row = e >> 7;
            const int c0 = e & (HD - 1);
            const int kg = k0 + row;
            float4 kv = make_float4(0.f, 0.f, 0.f, 0.f);
            float4 vv = make_float4(0.f, 0.f, 0.f, 0.f);
            if (kg < len) {
                kv = *(const float4*)&K[(size_t)(b * SEQ + kg) * DIM + h * HD + c0];
                vv = *(const float4*)&V[(size_t)(b * SEQ + kg) * DIM + h * HD + c0];
            }
            Kst[c0 + 0][row] = kv.x; Kst[c0 + 1][row] = kv.y;
            Kst[c0 + 2][row] = kv.z; Kst[c0 + 3][row] = kv.w;
            *(float4*)&Vs[row][c0] = vv;
        }
        __syncthreads();

        float acc[4][4] = {};
#pragma unroll 8
        for (int kk = 0; kk < HD; ++kk) {
            const float4 q4 = *(const float4*)&Qst[kk][si0];
            const float4 k4 = *(const float4*)&Kst[kk][sj0];
            const float qa[4] = {q4.x, q4.y, q4.z, q4.w};
            const float ka[4] = {k4.x, k4.y, k4.z, k4.w};
#pragma unroll
            for (int i = 0; i < 4; ++i)
#pragma unroll
                for (int j = 0; j < 4; ++j)
                    acc[i][j] = fmaf(qa[i], ka[j], acc[i][j]);
        }
#pragma unroll
        for (int i = 0; i < 4; ++i)
#pragma unroll
            for (int j = 0; j < 4; ++j) {
                const int jg = k0 + sj0 + j;
                Sc[si0 + i][sj0 + j] = (jg < len) ? acc[i][j] * scale : -1.0e9f;
            }
        __syncthreads();

        if (tid < BQ) {
            const int i = tid;
            const float m_old = mrow[i];
            float mx = m_old;
            for (int j = 0; j < BKT; ++j) mx = fmaxf(mx, Sc[i][j]);
            const float al = __expf(m_old - mx);
            float sum = 0.f;
            for (int j = 0; j < BKT; ++j) {
                const float p = __expf(Sc[i][j] - mx);
                Sc[i][j] = p;
                sum += p;
            }
            mrow[i] = mx;
            lrow[i] = lrow[i] * al + sum;
            alpha_s[i] = al;
        }
        __syncthreads();

#pragma unroll
        for (int i = 0; i < 4; ++i) {
            const float al = alpha_s[pi0 + i];
#pragma unroll
            for (int c = 0; c < 8; ++c) o[i][c] *= al;
        }
        for (int j = 0; j < BKT; ++j) {
            float p[4];
#pragma unroll
            for (int i = 0; i < 4; ++i) p[i] = Sc[pi0 + i][j];
            const float4 v0 = *(const float4*)&Vs[j][pc0];
            const float4 v1 = *(const float4*)&Vs[j][pc0 + 4];
            const float va[8] = {v0.x, v0.y, v0.z, v0.w, v1.x, v1.y, v1.z, v1.w};
#pragma unroll
            for (int i = 0; i < 4; ++i)
#pragma unroll
                for (int c = 0; c < 8; ++c)
                    o[i][c] = fmaf(p[i], va[c], o[i][c]);
        }
    }

#pragma unroll
    for (int i = 0; i < 4; ++i) {
        const float invl = 1.0f / lrow[pi0 + i];
        float4 w0, w1;
        w0.x = o[i][0] * invl; w0.y = o[i][1] * invl;
        w0.z = o[i][2] * invl; w0.w = o[i][3] * invl;
        w1.x = o[i][4] * invl; w1.y = o[i][5] * invl;
        w1.z = o[i][6] * invl; w1.w = o[i][7] * invl;
        float* op = &O[(size_t)(b * SEQ + q0 + pi0 + i) * DIM + h * HD + pc0];
        *(float4*)&op[0] = w0;
        *(float4*)&op[4] = w1;
    }
}

// ==================================================================== launch
extern "C" void kernel_launch(void* const* d_in, const int* in_sizes, int n_in,
                              void* d_out, int out_size, void* d_ws, size_t ws_size,
                              hipStream_t stream)
{
    const float* x        = (const float*)d_in[0];
    const int*   seq_lens = (const int*)d_in[1];
    const float* freqs    = (const float*)d_in[3];
    const float* Wq       = (const float*)d_in[4];
    const float* Wk       = (const float*)d_in[5];
    const float* Wv       = (const float*)d_in[6];
    const float* Wo       = (const float*)d_in[7];
    const float* bo       = (const float*)d_in[8];
    const float* gq       = (const float*)d_in[9];
    const float* gk       = (const float*)d_in[10];
    float* out = (float*)d_out;

    const size_t mat = (size_t)NROWS * DIM;       // 8.39M elems
    const size_t wsz = (size_t)DIM * DIM;         // 4.19M elems

    // ---- MFMA-path workspace layout (~185 MB) ----
    float*    Qb   = (float*)d_ws;                 // mat fp32
    float*    Kb   = Qb + mat;                     // mat fp32
    ushort_t* xh   = (ushort_t*)(Kb + mat);        // mat fp16
    ushort_t* wqh  = xh + mat;                     // 4 x wsz fp16 weights
    ushort_t* wkh  = wqh + wsz;
    ushort_t* wvh  = wkh + wsz;
    ushort_t* woh  = wvh + wsz;
    ushort_t* qbh  = woh + wsz;                    // mat bf16 (Q, pre-scaled)
    ushort_t* kbh  = qbh + mat;                    // mat bf16
    ushort_t* vtg  = kbh + mat;                    // mat bf16 (transposed V)
    ushort_t* abh  = vtg + mat;                    // mat fp16 (attn out)

    const size_t need = 2 * mat * sizeof(float)
                      + (mat + 4 * wsz + 4 * mat) * sizeof(ushort_t);

    if (ws_size >= need) {
        // ================= plain-fp16 MFMA path =================
        cvt_all_kernel<<<12288, 256, 0, stream>>>(
            x, Wq, Wk, Wv, Wo, xh, wqh, wkh, wvh, woh);

        const dim3 gg(DIM / 128, NROWS / 128);
        gemm_f16_kernel<0><<<gg, 256, 0, stream>>>(xh, wqh, nullptr, Qb, nullptr, NROWS, DIM, DIM);
        gemm_f16_kernel<0><<<gg, 256, 0, stream>>>(xh, wkh, nullptr, Kb, nullptr, NROWS, DIM, DIM);
        gemm_f16_kernel<1><<<gg, 256, 0, stream>>>(xh, wvh, nullptr, nullptr, vtg, NROWS, DIM, DIM);

        rmsnorm_rope_qk_kernel<<<dim3(NROWS, 2), 256, 0, stream>>>(
            Qb, gq, qbh, Kb, gk, kbh, freqs);

        attn_mfma_kernel<<<dim3(SEQ / AQ, NH, BATCH), 256, 0, stream>>>(qbh, kbh, vtg, seq_lens, abh);

        gemm_f16_kernel<0><<<gg, 256, 0, stream>>>(abh, woh, bo, out, nullptr, NROWS, DIM, DIM);
    } else {
        // ================= fp32 fallback (134 MB) =================
        float* Vb = Kb + mat;
        float* Ab = Vb + mat;
        const dim3 gemm_grid(DIM / BN, NROWS / BM);
        gemm_nt_kernel<<<gemm_grid, 256, 0, stream>>>(x, Wq, nullptr, Qb, NROWS, DIM, DIM);
        gemm_nt_kernel<<<gemm_grid, 256, 0, stream>>>(x, Wk, nullptr, Kb, NROWS, DIM, DIM);
        gemm_nt_kernel<<<gemm_grid, 256, 0, stream>>>(x, Wv, nullptr, Vb, NROWS, DIM, DIM);
        rmsnorm_rope_kernel<<<NROWS, 256, 0, stream>>>(Qb, gq, freqs);
        rmsnorm_rope_kernel<<<NROWS, 256, 0, stream>>>(Kb, gk, freqs);
        attn_kernel<<<dim3(SEQ / BQ, NH, BATCH), 256, 0, stream>>>(Qb, Kb, Vb, seq_lens, Ab);
        gemm_nt_kernel<<<gemm_grid, 256, 0, stream>>>(Ab, Wo, bo, out, NROWS, DIM, DIM);
    }
}